// Round 13
// baseline (818.239 us; speedup 1.0000x reference)
//
#include <hip/hip_runtime.h>

typedef unsigned short u16;
typedef __attribute__((ext_vector_type(8))) short bf16x8;
typedef __attribute__((ext_vector_type(4))) float f32x4;

#define S_LEN 2048
#define D_MODEL 2048
#define NHEAD 32
#define DHEAD 64
#define FF_DIM 8192
#define NTOK 4096

#define GBM 256
#define GBN 128
#define SLOT_U16 (GBM * 64 + GBN * 64)     // 24576 u16 = 48KB
#define GEMM_LDS_BYTES (3 * SLOT_U16 * 2)  // 144KB
#define GU_LDS_BYTES (2 * 65536)           // 128KB
#define DN_LDS_BYTES (2 * 65536)           // 128KB
#define QKV_SLOT_U16 (16384 + 3 * 8192)    // 40960 u16 = 80KB
#define QKV_LDS_BYTES (2 * QKV_SLOT_U16 * 2)  // 160KB (= full CU pool)

__device__ __forceinline__ u16 f2bf(float f) {
  union { float f; unsigned u; } v; v.f = f;
  unsigned r = v.u + 0x7fffu + ((v.u >> 16) & 1u);
  return (u16)(r >> 16);
}
__device__ __forceinline__ float bf2f(u16 b) {
  union { unsigned u; float f; } v; v.u = ((unsigned)b) << 16;
  return v.f;
}
__device__ __forceinline__ void gload_lds16(const void* g, void* l) {
  __builtin_amdgcn_global_load_lds(
      (const __attribute__((address_space(1))) void*)g,
      (__attribute__((address_space(3))) void*)l, 16, 0, 0);
}
__device__ __forceinline__ void barrier_f() {
  asm volatile("" ::: "memory");
  __builtin_amdgcn_s_barrier();
  asm volatile("" ::: "memory");
}

// ---------------- merged weight transpose + f32->bf16 convert (1 launch) ----------------
__global__ __launch_bounds__(256) void wconv_all(
    const float* __restrict__ wq, const float* __restrict__ wk,
    const float* __restrict__ wv, const float* __restrict__ wo,
    const float* __restrict__ wg, const float* __restrict__ wu,
    const float* __restrict__ wd,
    u16* wq_t, u16* wk_t, u16* wv_t, u16* wo_t,
    u16* wg_t, u16* wu_t, u16* wd_t) {
  __shared__ float tile[64][65];
  const int t = blockIdx.x;
  const float* in; u16* out; int Kd, Nd, lt;
  if (t < 4096) {
    const int m = t >> 10; lt = t & 1023;
    in  = m == 0 ? wq   : m == 1 ? wk   : m == 2 ? wv   : wo;
    out = m == 0 ? wq_t : m == 1 ? wk_t : m == 2 ? wv_t : wo_t;
    Kd = 2048; Nd = 2048;
  } else if (t < 12288) {
    const int m = (t - 4096) >> 12; lt = (t - 4096) & 4095;
    in = m == 0 ? wg : wu; out = m == 0 ? wg_t : wu_t;
    Kd = 2048; Nd = 8192;
  } else {
    lt = t - 12288; in = wd; out = wd_t; Kd = 8192; Nd = 2048;
  }
  const int ntx = Nd >> 6;
  const int n0 = (lt % ntx) * 64, k0 = (lt / ntx) * 64;
  const int tid = threadIdx.x;
  const int r = tid >> 4, c4 = (tid & 15) * 4;
#pragma unroll
  for (int rr = 0; rr < 4; ++rr) {
    int kr = rr * 16 + r;
    float4 v = *(const float4*)&in[(size_t)(k0 + kr) * Nd + n0 + c4];
    tile[kr][c4 + 0] = v.x; tile[kr][c4 + 1] = v.y;
    tile[kr][c4 + 2] = v.z; tile[kr][c4 + 3] = v.w;
  }
  __syncthreads();
#pragma unroll
  for (int rr = 0; rr < 4; ++rr) {
    int nr = rr * 16 + r;
    uint2 o;
    o.x = (unsigned)f2bf(tile[c4 + 0][nr]) | ((unsigned)f2bf(tile[c4 + 1][nr]) << 16);
    o.y = (unsigned)f2bf(tile[c4 + 2][nr]) | ((unsigned)f2bf(tile[c4 + 3][nr]) << 16);
    *(uint2*)&out[(size_t)(n0 + nr) * Kd + k0 + c4] = o;
  }
}

// ---------------- RMSNorm: f32 in -> bf16 out ----------------
__global__ __launch_bounds__(256) void rmsnorm_kernel(
    const float* __restrict__ in, const float* __restrict__ wt, u16* __restrict__ out) {
  const int row = blockIdx.x;
  const int tid = threadIdx.x;
  const float* rp = in + (size_t)row * D_MODEL;
  float4 a = *(const float4*)&rp[tid * 8];
  float4 b = *(const float4*)&rp[tid * 8 + 4];
  float ss = a.x*a.x + a.y*a.y + a.z*a.z + a.w*a.w
           + b.x*b.x + b.y*b.y + b.z*b.z + b.w*b.w;
#pragma unroll
  for (int d = 1; d < 64; d <<= 1) ss += __shfl_xor(ss, d);
  __shared__ float red[4];
  if ((tid & 63) == 0) red[tid >> 6] = ss;
  __syncthreads();
  float tot = red[0] + red[1] + red[2] + red[3];
  float rms = rsqrtf(tot * (1.f / (float)D_MODEL) + 1e-6f);
  float4 wa = *(const float4*)&wt[tid * 8];
  float4 wb = *(const float4*)&wt[tid * 8 + 4];
  uint4 o;
  o.x = (unsigned)f2bf(a.x * rms * wa.x) | ((unsigned)f2bf(a.y * rms * wa.y) << 16);
  o.y = (unsigned)f2bf(a.z * rms * wa.z) | ((unsigned)f2bf(a.w * rms * wa.w) << 16);
  o.z = (unsigned)f2bf(b.x * rms * wb.x) | ((unsigned)f2bf(b.y * rms * wb.y) << 16);
  o.w = (unsigned)f2bf(b.z * rms * wb.z) | ((unsigned)f2bf(b.w * rms * wb.w) << 16);
  *(uint4*)&out[(size_t)row * D_MODEL + tid * 8] = o;
}

// ---------------- staging: RN rows x 64 K into region (swizzled source) ----------------
template <int RN>
__device__ __forceinline__ void stage_op(const u16* src, int ldE,
                                         int row0, int ktbyte, u16* slot,
                                         int w, int lane) {
  constexpr int L = RN / 64;
#pragma unroll
  for (int l = 0; l < L; ++l) {
    const int dst = l * 8192 + w * 1024;
    const int dl = dst + lane * 16;
    const int srcb = dl ^ (((dl >> 7) & 7) << 4);
    const int row = srcb >> 7, colb = srcb & 127;
    gload_lds16((const char*)src + (size_t)(row0 + row) * ldE * 2 + ktbyte + colb,
                (char*)slot + dst);
  }
}

// ---------------- gemm3: ring-3, counted vmcnt, swizzled LDS (O-proj) ----------------
template <int EPI>
__global__ __launch_bounds__(512, 2) void gemm3(
    const u16* __restrict__ A, const u16* __restrict__ Bt,
    int M, int N, int K,
    float* ofl, const float* __restrict__ xres) {
  extern __shared__ u16 smem[];
  const int tid = threadIdx.x;
  const int w = tid >> 6, lane = tid & 63;
  const int nwg = gridDim.x;
  const int bid = blockIdx.x;
  const int sw = (bid & 7) * (nwg >> 3) + (bid >> 3);
  const int mtiles = M / GBM;
  const int m0 = (sw % mtiles) * GBM;
  const int n0 = (sw / mtiles) * GBN;
  const int wm = w >> 1, wn = w & 1;
  const int KT = K / 64;
  const int ql = lane & 15, qh = (lane >> 4) * 16;
  f32x4 acc[4][4] = {};

  u16* const s0A = smem;
  stage_op<GBM>(A, K, m0, 0, s0A + 0 * SLOT_U16, w, lane);
  stage_op<GBN>(Bt, K, n0, 0, s0A + 0 * SLOT_U16 + GBM * 64, w, lane);
  stage_op<GBM>(A, K, m0, 128, s0A + 1 * SLOT_U16, w, lane);
  stage_op<GBN>(Bt, K, n0, 128, s0A + 1 * SLOT_U16 + GBM * 64, w, lane);
  asm volatile("s_waitcnt vmcnt(6)" ::: "memory");
  __builtin_amdgcn_s_barrier();
  asm volatile("" ::: "memory");

  for (int t = 0; t < KT; ++t) {
    const int s = t % 3;
    if (t + 2 < KT) {
      const int s2 = (t + 2) % 3;
      const int kb = (t + 2) * 128;
      stage_op<GBM>(A, K, m0, kb, s0A + s2 * SLOT_U16, w, lane);
      stage_op<GBN>(Bt, K, n0, kb, s0A + s2 * SLOT_U16 + GBM * 64, w, lane);
    }
    const u16* sA = s0A + s * SLOT_U16;
    const u16* sB = sA + GBM * 64;
#pragma unroll
    for (int kk = 0; kk < 2; ++kk) {
      bf16x8 af[4], bq[4];
      const int cb = kk * 64 + qh;
#pragma unroll
      for (int i = 0; i < 4; ++i) {
        const int row = wm * 64 + i * 16 + ql;
        af[i] = *(const bf16x8*)((const char*)sA + (((row << 7) + cb) ^ ((row & 7) << 4)));
      }
#pragma unroll
      for (int j = 0; j < 4; ++j) {
        const int row = wn * 64 + j * 16 + ql;
        bq[j] = *(const bf16x8*)((const char*)sB + (((row << 7) + cb) ^ ((row & 7) << 4)));
      }
      __builtin_amdgcn_s_setprio(1);
#pragma unroll
      for (int i = 0; i < 4; ++i)
#pragma unroll
        for (int j = 0; j < 4; ++j)
          acc[i][j] = __builtin_amdgcn_mfma_f32_16x16x32_bf16(af[i], bq[j], acc[i][j], 0, 0, 0);
      __builtin_amdgcn_s_setprio(0);
    }
    if (t < KT - 2) asm volatile("s_waitcnt vmcnt(6)" ::: "memory");
    else            asm volatile("s_waitcnt vmcnt(0)" ::: "memory");
    __builtin_amdgcn_s_barrier();
    asm volatile("" ::: "memory");
  }

  const int rbase = (lane >> 4) * 4;
#pragma unroll
  for (int i = 0; i < 4; ++i) {
#pragma unroll
    for (int j = 0; j < 4; ++j) {
      const int grow0 = m0 + wm * 64 + i * 16 + rbase;
      const int gcol = n0 + wn * 64 + j * 16 + ql;
#pragma unroll
      for (int r = 0; r < 4; ++r) {
        const int grow = grow0 + r;
        ofl[(size_t)grow * N + gcol] = xres[(size_t)grow * N + gcol] + acc[i][j][r];
      }
    }
  }
}

// ---------------- fused QKV GEMM: triple-B BN=128, ring-2 x 80KB (160KB LDS) ----------------
// q = rope(A@Bq^T), k = rope(A@Bk^T), vt = headT(A@Bv^T)
// BM=256, 8 waves (4M x 2N), wave out 64x64 per output; 96 MFMA / 10 loads per K-tile.
__global__ __launch_bounds__(512, 1) void gemm_qkv(
    const u16* __restrict__ A, const u16* __restrict__ Bq,
    const u16* __restrict__ Bk, const u16* __restrict__ Bv,
    int M, int N, int K,
    u16* __restrict__ oq, u16* __restrict__ ok, u16* __restrict__ ovt,
    const float* __restrict__ fc, const float* __restrict__ fs) {
  extern __shared__ u16 smem[];
  const int tid = threadIdx.x;
  const int w = tid >> 6, lane = tid & 63;
  const int nwg = gridDim.x, bid = blockIdx.x;
  const int sw = (bid & 7) * (nwg >> 3) + (bid >> 3);
  const int mtiles = M / 256;
  const int m0 = (sw % mtiles) * 256;
  const int n0 = (sw / mtiles) * 128;
  const int wm = w >> 1, wn = w & 1;
  const int KT = K / 64;
  const int ql = lane & 15, qh = (lane >> 4) * 16;
  f32x4 aq[4][4] = {}, ak[4][4] = {}, av[4][4] = {};

  auto stage = [&](int t, int slot) {
    u16* base = smem + slot * QKV_SLOT_U16;
    const int kb = t * 128;
    stage_op<256>(A,  K, m0, kb, base,          w, lane);   // 4 loads
    stage_op<128>(Bq, K, n0, kb, base + 16384, w, lane);    // 2
    stage_op<128>(Bk, K, n0, kb, base + 24576, w, lane);    // 2
    stage_op<128>(Bv, K, n0, kb, base + 32768, w, lane);    // 2
  };

  stage(0, 0);
  for (int t = 0; t < KT; ++t) {
    if (t + 1 < KT) {
      stage(t + 1, (t + 1) & 1);
      asm volatile("s_waitcnt vmcnt(10)" ::: "memory");
    } else {
      asm volatile("s_waitcnt vmcnt(0)" ::: "memory");
    }
    __builtin_amdgcn_s_barrier();
    asm volatile("" ::: "memory");

    const u16* sA = smem + (t & 1) * QKV_SLOT_U16;
    const u16* sQ = sA + 16384;
    const u16* sK = sA + 24576;
    const u16* sV = sA + 32768;
#pragma unroll
    for (int kk = 0; kk < 2; ++kk) {
      bf16x8 af[4], bb[4];
      const int cb = kk * 64 + qh;
#pragma unroll
      for (int i = 0; i < 4; ++i) {
        const int row = wm * 64 + i * 16 + ql;
        af[i] = *(const bf16x8*)((const char*)sA + (((row << 7) + cb) ^ ((row & 7) << 4)));
      }
      __builtin_amdgcn_s_setprio(1);
#pragma unroll
      for (int j = 0; j < 4; ++j) {
        const int row = wn * 64 + j * 16 + ql;
        bb[j] = *(const bf16x8*)((const char*)sQ + (((row << 7) + cb) ^ ((row & 7) << 4)));
      }
#pragma unroll
      for (int i = 0; i < 4; ++i)
#pragma unroll
        for (int j = 0; j < 4; ++j)
          aq[i][j] = __builtin_amdgcn_mfma_f32_16x16x32_bf16(af[i], bb[j], aq[i][j], 0, 0, 0);
#pragma unroll
      for (int j = 0; j < 4; ++j) {
        const int row = wn * 64 + j * 16 + ql;
        bb[j] = *(const bf16x8*)((const char*)sK + (((row << 7) + cb) ^ ((row & 7) << 4)));
      }
#pragma unroll
      for (int i = 0; i < 4; ++i)
#pragma unroll
        for (int j = 0; j < 4; ++j)
          ak[i][j] = __builtin_amdgcn_mfma_f32_16x16x32_bf16(af[i], bb[j], ak[i][j], 0, 0, 0);
#pragma unroll
      for (int j = 0; j < 4; ++j) {
        const int row = wn * 64 + j * 16 + ql;
        bb[j] = *(const bf16x8*)((const char*)sV + (((row << 7) + cb) ^ ((row & 7) << 4)));
      }
#pragma unroll
      for (int i = 0; i < 4; ++i)
#pragma unroll
        for (int j = 0; j < 4; ++j)
          av[i][j] = __builtin_amdgcn_mfma_f32_16x16x32_bf16(af[i], bb[j], av[i][j], 0, 0, 0);
      __builtin_amdgcn_s_setprio(0);
    }
    __builtin_amdgcn_s_barrier();
    asm volatile("" ::: "memory");
  }

  const int rbase = (lane >> 4) * 4;
#pragma unroll
  for (int i = 0; i < 4; ++i) {
#pragma unroll
    for (int j = 0; j < 4; ++j) {
      const int grow0 = m0 + wm * 64 + i * 16 + rbase;
      const int c = n0 + wn * 64 + j * 16 + ql;
      const int i2 = (c & 63) >> 1;
      const int odd = c & 1;
      // V: head-transposed packed store
      {
        const int b = grow0 >> 11, s4 = grow0 & (S_LEN - 1);
        const int h = c >> 6, dh = c & 63;
        uint2 ov;
        ov.x = (unsigned)f2bf(av[i][j][0]) | ((unsigned)f2bf(av[i][j][1]) << 16);
        ov.y = (unsigned)f2bf(av[i][j][2]) | ((unsigned)f2bf(av[i][j][3]) << 16);
        *(uint2*)&ovt[((((size_t)b * NHEAD + h) * DHEAD + dh) << 11) + s4] = ov;
      }
#pragma unroll
      for (int r = 0; r < 4; ++r) {
        const int grow = grow0 + r;
        const int s4 = grow & (S_LEN - 1);
        const float cs = fc[s4 * 32 + i2], sn = fs[s4 * 32 + i2];
        {
          const float v = aq[i][j][r];
          const float p = __shfl_xor(v, 1);
          const float outv = odd ? (p * sn + v * cs) : (v * cs - p * sn);
          oq[(size_t)grow * D_MODEL + c] = f2bf(outv);
        }
        {
          const float v = ak[i][j][r];
          const float p = __shfl_xor(v, 1);
          const float outv = odd ? (p * sn + v * cs) : (v * cs - p * sn);
          ok[(size_t)grow * D_MODEL + c] = f2bf(outv);
        }
      }
    }
  }
}

// ---------------- fused gate+up GEMM: 4-phase pipelined (T3+T4), ring-2 ----------------
__global__ __launch_bounds__(512, 1) void gemm_gu(
    const u16* __restrict__ A, const u16* __restrict__ Bg, const u16* __restrict__ Bu,
    int M, int N, int K, u16* __restrict__ o0) {
  extern __shared__ u16 smem[];
  const int tid = threadIdx.x;
  const int w = tid >> 6, lane = tid & 63;
  const int nwg = gridDim.x, bid = blockIdx.x;
  const int sw = (bid & 7) * (nwg >> 3) + (bid >> 3);
  const int mtiles = M / 256;
  const int m0 = (sw % mtiles) * 256;
  const int n0 = (sw / mtiles) * 128;
  const int wm = w >> 1, wn = w & 1;
  const int KT = K / 64;
  const int ql = lane & 15, qh = (lane >> 4) * 16;
  f32x4 accg[4][4] = {}, accu[4][4] = {};

  int abyt[4][2], bbyt[4][2];
#pragma unroll
  for (int i = 0; i < 4; ++i)
#pragma unroll
    for (int kk = 0; kk < 2; ++kk) {
      const int ra = wm * 64 + i * 16 + ql;
      abyt[i][kk] = ((ra << 7) + kk * 64 + qh) ^ ((ra & 7) << 4);
      const int rb = wn * 64 + i * 16 + ql;
      bbyt[i][kk] = ((rb << 7) + kk * 64 + qh) ^ ((rb & 7) << 4);
    }

  auto stage_E = [&](int t, int slot) {
    u16* base = smem + slot * 32768;
    stage_op<256>(A,  K, m0, t * 128, base,         w, lane);
    stage_op<128>(Bg, K, n0, t * 128, base + 16384, w, lane);
  };
  auto stage_L = [&](int t, int slot) {
    u16* base = smem + slot * 32768;
    stage_op<128>(Bu, K, n0, t * 128, base + 24576, w, lane);
  };

  stage_E(0, 0);
  stage_L(0, 0);
  asm volatile("s_waitcnt vmcnt(2)" ::: "memory");
  barrier_f();

  for (int t = 0; t < KT; ++t) {
    const bool last = (t == KT - 1);
    const char* sA = (const char*)smem + (t & 1) * 65536;
    const char* sG = sA + 32768;
    const char* sU = sA + 49152;
    bf16x8 af[4], bb[4];
#pragma unroll
    for (int i = 0; i < 4; ++i) af[i] = *(const bf16x8*)(sA + abyt[i][0]);
#pragma unroll
    for (int j = 0; j < 4; ++j) bb[j] = *(const bf16x8*)(sG + bbyt[j][0]);
    if (!last) {
      stage_E(t + 1, (t + 1) & 1);
      asm volatile("s_waitcnt vmcnt(6)" ::: "memory");
    } else {
      asm volatile("s_waitcnt vmcnt(0)" ::: "memory");
    }
    barrier_f();
    __builtin_amdgcn_s_setprio(1);
#pragma unroll
    for (int i = 0; i < 4; ++i)
#pragma unroll
      for (int j = 0; j < 4; ++j)
        accg[i][j] = __builtin_amdgcn_mfma_f32_16x16x32_bf16(af[i], bb[j], accg[i][j], 0, 0, 0);
    __builtin_amdgcn_s_setprio(0);
    barrier_f();
#pragma unroll
    for (int j = 0; j < 4; ++j) bb[j] = *(const bf16x8*)(sU + bbyt[j][0]);
    if (!last) stage_L(t + 1, (t + 1) & 1);
    barrier_f();
    __builtin_amdgcn_s_setprio(1);
#pragma unroll
    for (int i = 0; i < 4; ++i)
#pragma unroll
      for (int j = 0; j < 4; ++j)
        accu[i][j] = __builtin_amdgcn_mfma_f32_16x16x32_bf16(af[i], bb[j], accu[i][j], 0, 0, 0);
    __builtin_amdgcn_s_setprio(0);
    barrier_f();
#pragma unroll
    for (int i = 0; i < 4; ++i) af[i] = *(const bf16x8*)(sA + abyt[i][1]);
#pragma unroll
    for (int j = 0; j < 4; ++j) bb[j] = *(const bf16x8*)(sG + bbyt[j][1]);
    barrier_f();
    __builtin_amdgcn_s_setprio(1);
#pragma unroll
    for (int i = 0; i < 4; ++i)
#pragma unroll
      for (int j = 0; j < 4; ++j)
        accg[i][j] = __builtin_amdgcn_mfma_f32_16x16x32_bf16(af[i], bb[j], accg[i][j], 0, 0, 0);
    __builtin_amdgcn_s_setprio(0);
    barrier_f();
#pragma unroll
    for (int j = 0; j < 4; ++j) bb[j] = *(const bf16x8*)(sU + bbyt[j][1]);
    if (!last) asm volatile("s_waitcnt vmcnt(2)" ::: "memory");
    barrier_f();
    __builtin_amdgcn_s_setprio(1);
#pragma unroll
    for (int i = 0; i < 4; ++i)
#pragma unroll
      for (int j = 0; j < 4; ++j)
        accu[i][j] = __builtin_amdgcn_mfma_f32_16x16x32_bf16(af[i], bb[j], accu[i][j], 0, 0, 0);
    __builtin_amdgcn_s_setprio(0);
    barrier_f();
  }

  const int rbase = (lane >> 4) * 4;
#pragma unroll
  for (int i = 0; i < 4; ++i) {
#pragma unroll
    for (int j = 0; j < 4; ++j) {
      const int grow0 = m0 + wm * 64 + i * 16 + rbase;
      const int gcol = n0 + wn * 64 + j * 16 + ql;
#pragma unroll
      for (int r = 0; r < 4; ++r) {
        const float g = accg[i][j][r];
        const float u = accu[i][j][r];
        const float sg = g / (1.f + __expf(-g));
        o0[(size_t)(grow0 + r) * N + gcol] = f2bf(sg * u);
      }
    }
  }
}

// ---------------- down GEMM: ring-2, 256x256, split-K=2, bf16 partials ----------------
__global__ __launch_bounds__(512, 1) void gemm_dn(
    const u16* __restrict__ A, const u16* __restrict__ Bt,
    int M, int N, int Kld, u16* __restrict__ pbuf) {
  extern __shared__ u16 smem[];
  const int tid = threadIdx.x;
  const int w = tid >> 6, lane = tid & 63;
  const int nwg = gridDim.x, bid = blockIdx.x;
  const int sw = (bid & 7) * (nwg >> 3) + (bid >> 3);
  const int mtiles = M / 256;
  const int tilesPerSplit = mtiles * (N / 256);
  const int split = sw / tilesPerSplit;
  const int tt = sw % tilesPerSplit;
  const int m0 = (tt % mtiles) * 256;
  const int n0 = (tt / mtiles) * 256;
  const u16* Ap = A + (size_t)split * (Kld / 2);
  const u16* Bp = Bt + (size_t)split * (Kld / 2);
  u16* op = pbuf + (size_t)split * M * N;
  const int wm = w >> 2, wn = w & 3;
  const int KT = (Kld / 2) / 64;
  const int ql = lane & 15, qh = (lane >> 4) * 16;
  f32x4 acc[8][4] = {};

  auto stage = [&](int t, int slot) {
    u16* base = smem + slot * 32768;
    const int kb = t * 128;
    stage_op<256>(Ap, Kld, m0, kb, base,         w, lane);
    stage_op<256>(Bp, Kld, n0, kb, base + 16384, w, lane);
  };

  stage(0, 0);
  for (int t = 0; t < KT; ++t) {
    if (t + 1 < KT) {
      stage(t + 1, (t + 1) & 1);
      asm volatile("s_waitcnt vmcnt(8)" ::: "memory");
    } else {
      asm volatile("s_waitcnt vmcnt(0)" ::: "memory");
    }
    __builtin_amdgcn_s_barrier();
    asm volatile("" ::: "memory");

    const u16* sA = smem + (t & 1) * 32768;
    const u16* sB = sA + 16384;
#pragma unroll
    for (int kk = 0; kk < 2; ++kk) {
      bf16x8 af[8], bq[4];
      const int cb = kk * 64 + qh;
#pragma unroll
      for (int i = 0; i < 8; ++i) {
        const int row = wm * 128 + i * 16 + ql;
        af[i] = *(const bf16x8*)((const char*)sA + (((row << 7) + cb) ^ ((row & 7) << 4)));
      }
#pragma unroll
      for (int j = 0; j < 4; ++j) {
        const int row = wn * 64 + j * 16 + ql;
        bq[j] = *(const bf16x8*)((const char*)sB + (((row << 7) + cb) ^ ((row & 7) << 4)));
      }
      __builtin_amdgcn_s_setprio(1);
#pragma unroll
      for (int i = 0; i < 8; ++i)
#pragma unroll
        for (int j = 0; j < 4; ++j)
          acc[i][j] = __builtin_amdgcn_mfma_f32_16x16x32_bf16(af[i], bq[j], acc[i][j], 0, 0, 0);
      __builtin_amdgcn_s_setprio(0);
    }
    __builtin_amdgcn_s_barrier();
    asm volatile("" ::: "memory");
  }

  const int rbase = (lane >> 4) * 4;
#pragma unroll
  for (int i = 0; i < 8; ++i) {
#pragma unroll
    for (int j = 0; j < 4; ++j) {
      const int grow0 = m0 + wm * 128 + i * 16 + rbase;
      const int gcol = n0 + wn * 64 + j * 16 + ql;
#pragma unroll
      for (int r = 0; r < 4; ++r)
        op[(size_t)(grow0 + r) * N + gcol] = f2bf(acc[i][j][r]);
    }
  }
}

// ---------------- split-K combine: out += p0 + p1 (bf16 partials) ----------------
__global__ __launch_bounds__(256) void combine_kernel(
    const u16* __restrict__ p0, const u16* __restrict__ p1, float* __restrict__ out) {
  const size_t idx = ((size_t)blockIdx.x * 256 + threadIdx.x) * 8;
  bf16x8 a = *(const bf16x8*)&p0[idx];
  bf16x8 b = *(const bf16x8*)&p1[idx];
  float4 c0 = *(const float4*)&out[idx];
  float4 c1 = *(const float4*)&out[idx + 4];
  c0.x += bf2f((u16)a[0]) + bf2f((u16)b[0]);
  c0.y += bf2f((u16)a[1]) + bf2f((u16)b[1]);
  c0.z += bf2f((u16)a[2]) + bf2f((u16)b[2]);
  c0.w += bf2f((u16)a[3]) + bf2f((u16)b[3]);
  c1.x += bf2f((u16)a[4]) + bf2f((u16)b[4]);
  c1.y += bf2f((u16)a[5]) + bf2f((u16)b[5]);
  c1.z += bf2f((u16)a[6]) + bf2f((u16)b[6]);
  c1.w += bf2f((u16)a[7]) + bf2f((u16)b[7]);
  *(float4*)&out[idx] = c0;
  *(float4*)&out[idx + 4] = c1;
}

// ---------------- Flash attention (causal), swapped-QK^T, swizzled, ring-2 ----------------
__global__ __launch_bounds__(256) void attn_kernel(
    const u16* __restrict__ q, const u16* __restrict__ k,
    const u16* __restrict__ vt, u16* __restrict__ o) {
  __shared__ u16 lKV[2][128 * 64];
  __shared__ u16 lP[4][32 * 64];
  const int tid = threadIdx.x, w = tid >> 6, lane = tid & 63;
  const int ql = lane & 15, qh16 = (lane >> 4) * 16, rbase = (lane >> 4) * 4;
  const int bx = (int)gridDim.x - 1 - (int)blockIdx.x;
  const int bh = blockIdx.y, b = bh >> 5, h = bh & 31;
  const int q0 = bx * 128;
  const int nt = 2 * bx + 2;
  const char* kbase = (const char*)(k + ((size_t)b * S_LEN) * D_MODEL + h * DHEAD);
  const char* vbase = (const char*)(vt + (size_t)bh * DHEAD * S_LEN);

  bf16x8 qf[2][2];
#pragma unroll
  for (int i = 0; i < 2; ++i) {
    const size_t tok = (size_t)b * S_LEN + q0 + w * 32 + i * 16 + ql;
#pragma unroll
    for (int kk = 0; kk < 2; ++kk) {
      bf16x8 v = *(const bf16x8*)&q[tok * D_MODEL + h * DHEAD + kk * 32 + (lane >> 4) * 8];
#pragma unroll
      for (int e = 0; e < 8; ++e) v[e] = (short)f2bf(bf2f((u16)v[e]) * 0.125f);
      qf[i][kk] = v;
    }
  }

  float m[2] = {-1e30f, -1e30f}, l[2] = {0.f, 0.f};
  f32x4 oacc[2][4] = {};

  auto stage = [&](int kt, int slot) {
    const int s0 = kt * 64;
#pragma unroll
    for (int lo = 0; lo < 2; ++lo) {
      const int dst = lo * 4096 + w * 1024;
      const int dl = dst + lane * 16;
      const int srcb = dl ^ (((dl >> 7) & 7) << 4);
      const int row = srcb >> 7, colb = srcb & 127;
      gload_lds16(kbase + (size_t)(s0 + row) * (D_MODEL * 2) + colb,
                  (char*)&lKV[slot][0] + dst);
    }
#pragma unroll
    for (int lo = 0; lo < 2; ++lo) {
      const int dst = lo * 4096 + w * 1024;
      const int dl = dst + lane * 16;
      const int srcb = dl ^ (((dl >> 7) & 7) << 4);
      const int row = srcb >> 7, colb = srcb & 127;
      gload_lds16(vbase + (size_t)row * (S_LEN * 2) + (size_t)s0 * 2 + colb,
                  (char*)&lKV[slot][64 * 64] + dst);
    }
  };

  stage(0, 0);
  for (int kt = 0; kt < nt; ++kt) {
    if (kt + 1 < nt) {
      stage(kt + 1, (kt + 1) & 1);
      asm volatile("s_waitcnt vmcnt(4)" ::: "memory");
    } else {
      asm volatile("s_waitcnt vmcnt(0)" ::: "memory");
    }
    __builtin_amdgcn_s_barrier();
    asm volatile("" ::: "memory");

    const u16* sK = &lKV[kt & 1][0];
    const u16* sV = &lKV[kt & 1][64 * 64];
    const int s0 = kt * 64;

    f32x4 scT[2][4] = {};
#pragma unroll
    for (int kk = 0; kk < 2; ++kk) {
#pragma unroll
      for (int j = 0; j < 4; ++j) {
        const int row = j * 16 + ql;
        bf16x8 kf = *(const bf16x8*)((const char*)sK +
                      (((row << 7) + kk * 64 + qh16) ^ ((row & 7) << 4)));
#pragma unroll
        for (int i = 0; i < 2; ++i)
          scT[i][j] = __builtin_amdgcn_mfma_f32_16x16x32_bf16(kf, qf[i][kk], scT[i][j], 0, 0, 0);
      }
    }
    const bool diag = (s0 + 63 > q0);
#pragma unroll
    for (int i = 0; i < 2; ++i) {
      const int qrow = q0 + w * 32 + i * 16 + ql;
      if (diag) {
#pragma unroll
        for (int j = 0; j < 4; ++j)
#pragma unroll
          for (int r = 0; r < 4; ++r)
            if (s0 + j * 16 + rbase + r > qrow) scT[i][j][r] = -1e30f;
      }
      float mx = scT[i][0][0];
#pragma unroll
      for (int j = 0; j < 4; ++j)
#pragma unroll
        for (int r = 0; r < 4; ++r) mx = fmaxf(mx, scT[i][j][r]);
      mx = fmaxf(mx, __shfl_xor(mx, 16));
      mx = fmaxf(mx, __shfl_xor(mx, 32));
      const float mnew = fmaxf(m[i], mx);
      const float alpha = __expf(m[i] - mnew);
      m[i] = mnew;
      float rs = 0.f;
#pragma unroll
      for (int j = 0; j < 4; ++j)
#pragma unroll
        for (int r = 0; r < 4; ++r) {
          const float p = __expf(scT[i][j][r] - mnew);
          scT[i][j][r] = p;
          rs += p;
        }
      rs += __shfl_xor(rs, 16);
      rs += __shfl_xor(rs, 32);
      l[i] = l[i] * alpha + rs;
#pragma unroll
      for (int rr = 0; rr < 4; ++rr) {
        const float ar = __shfl(alpha, rbase + rr);
#pragma unroll
        for (int j = 0; j < 4; ++j) oacc[i][j][rr] *= ar;
      }
      const int prow = i * 16 + ql;
      const int pb = prow << 7;
      const int swz = (prow & 7) << 4;
#pragma unroll
      for (int j = 0; j < 4; ++j) {
#pragma unroll
        for (int rp = 0; rp < 2; ++rp) {
          const int col = j * 16 + rbase + rp * 2;
          unsigned pk = (unsigned)f2bf(scT[i][j][rp * 2]) |
                        ((unsigned)f2bf(scT[i][j][rp * 2 + 1]) << 16);
          *(unsigned*)((char*)lP[w] + ((pb + col * 2) ^ swz)) = pk;
        }
      }
    }
#pragma unroll
    for (int i = 0; i < 2; ++i) {
      const int arow = i * 16 + ql;
#pragma unroll
      for (int kk = 0; kk < 2; ++kk) {
        bf16x8 pa = *(const bf16x8*)((const char*)lP[w] +
                      (((arow << 7) + kk * 64 + qh16) ^ ((arow & 7) << 4)));
#pragma unroll
        for (int j = 0; j < 4; ++j) {
          const int vrow = j * 16 + ql;
          bf16x8 bv = *(const bf16x8*)((const char*)sV +
                        (((vrow << 7) + kk * 64 + qh16) ^ ((vrow & 7) << 4)));
          oacc[i][j] = __builtin_amdgcn_mfma_f32_16x16x32_bf16(pa, bv, oacc[i][j], 0, 0, 0);
        }
      }
    }
    __builtin_amdgcn_s_barrier();
    asm volatile("" ::: "memory");
  }
#pragma unroll
  for (int i = 0; i < 2; ++i) {
#pragma unroll
    for (int rr = 0; rr < 4; ++rr) {
      const float linv = 1.f / __shfl(l[i], rbase + rr);
      const size_t tok = (size_t)b * S_LEN + q0 + w * 32 + i * 16 + rbase + rr;
#pragma unroll
      for (int j = 0; j < 4; ++j)
        o[tok * D_MODEL + h * DHEAD + j * 16 + ql] = f2bf(oacc[i][j][rr] * linv);
    }
  }
}

// ---------------- host ----------------
extern "C" void kernel_launch(void* const* d_in, const int* in_sizes, int n_in,
                              void* d_out, int out_size, void* d_ws, size_t ws_size,
                              hipStream_t stream) {
  (void)in_sizes; (void)n_in; (void)out_size; (void)ws_size;
  const float* x  = (const float*)d_in[0];
  const float* fc = (const float*)d_in[1];
  const float* fs = (const float*)d_in[2];
  const float* wq = (const float*)d_in[4];
  const float* wk = (const float*)d_in[5];
  const float* wv = (const float*)d_in[6];
  const float* wo = (const float*)d_in[7];
  const float* wg = (const float*)d_in[8];
  const float* wu = (const float*)d_in[9];
  const float* wd = (const float*)d_in[10];
  const float* n1 = (const float*)d_in[11];
  const float* n2 = (const float*)d_in[12];
  float* out = (float*)d_out;

  char* ws = (char*)d_ws;
  size_t off = 0;
  auto alloc = [&](size_t bytes) { void* p = ws + off; off += (bytes + 255) & ~(size_t)255; return p; };
  u16* wq_t = (u16*)alloc((size_t)D_MODEL * D_MODEL * 2);
  u16* wk_t = (u16*)alloc((size_t)D_MODEL * D_MODEL * 2);
  u16* wv_t = (u16*)alloc((size_t)D_MODEL * D_MODEL * 2);
  u16* wo_t = (u16*)alloc((size_t)D_MODEL * D_MODEL * 2);
  u16* wg_t = (u16*)alloc((size_t)D_MODEL * FF_DIM * 2);
  u16* wu_t = (u16*)alloc((size_t)D_MODEL * FF_DIM * 2);
  u16* wd_t = (u16*)alloc((size_t)FF_DIM * D_MODEL * 2);
  u16* hn   = (u16*)alloc((size_t)NTOK * D_MODEL * 2);
  u16* qb   = (u16*)alloc((size_t)NTOK * D_MODEL * 2);
  u16* kb   = (u16*)alloc((size_t)NTOK * D_MODEL * 2);
  u16* vtb  = (u16*)alloc((size_t)NTOK * D_MODEL * 2);
  u16* ao   = (u16*)alloc((size_t)NTOK * D_MODEL * 2);
  u16* gt   = (u16*)alloc((size_t)NTOK * FF_DIM * 2);
  u16* pbuf = qb;   // bf16 split-K partials reuse dead qb/kb region

  wconv_all<<<16384, 256, 0, stream>>>(wq, wk, wv, wo, wg, wu, wd,
                                       wq_t, wk_t, wv_t, wo_t, wg_t, wu_t, wd_t);
  rmsnorm_kernel<<<NTOK, 256, 0, stream>>>(x, n1, hn);
  // fused QKV (triple-B BN=128, 160KB LDS): grid 16*16 = 256 = one full-machine round
  gemm_qkv<<<256, 512, QKV_LDS_BYTES, stream>>>(hn, wq_t, wk_t, wv_t,
                                                NTOK, D_MODEL, D_MODEL,
                                                qb, kb, vtb, fc, fs);
  attn_kernel<<<dim3(16, 64), 256, 0, stream>>>(qb, kb, vtb, ao);
  gemm3<2><<<256, 512, GEMM_LDS_BYTES, stream>>>(ao, wo_t, NTOK, D_MODEL, D_MODEL, out, x);
  rmsnorm_kernel<<<NTOK, 256, 0, stream>>>(out, n2, hn);
  gemm_gu<<<1024, 512, GU_LDS_BYTES, stream>>>(hn, wg_t, wu_t, NTOK, FF_DIM, D_MODEL, gt);
  gemm_dn<<<256, 512, DN_LDS_BYTES, stream>>>(gt, wd_t, NTOK, D_MODEL, FF_DIM, pbuf);
  combine_kernel<<<(NTOK * D_MODEL) / (256 * 8), 256, 0, stream>>>(
      pbuf, pbuf + (size_t)NTOK * D_MODEL, out);
}

// Round 14
// 798.148 us; speedup vs baseline: 1.0252x; 1.0252x over previous
//
#include <hip/hip_runtime.h>

typedef unsigned short u16;
typedef __attribute__((ext_vector_type(8))) short bf16x8;
typedef __attribute__((ext_vector_type(4))) float f32x4;

#define S_LEN 2048
#define D_MODEL 2048
#define NHEAD 32
#define DHEAD 64
#define FF_DIM 8192
#define NTOK 4096

#define GU_LDS_BYTES (2 * 65536)              // 128KB
#define DN_LDS_BYTES (2 * 65536)              // 128KB
#define QKV_SLOT_U16 (16384 + 3 * 4096)       // 28672 u16 = 56KB
#define QKV_LDS_BYTES (2 * QKV_SLOT_U16 * 2)  // 112KB

__device__ __forceinline__ u16 f2bf(float f) {
  union { float f; unsigned u; } v; v.f = f;
  unsigned r = v.u + 0x7fffu + ((v.u >> 16) & 1u);
  return (u16)(r >> 16);
}
__device__ __forceinline__ float bf2f(u16 b) {
  union { unsigned u; float f; } v; v.u = ((unsigned)b) << 16;
  return v.f;
}
__device__ __forceinline__ void gload_lds16(const void* g, void* l) {
  __builtin_amdgcn_global_load_lds(
      (const __attribute__((address_space(1))) void*)g,
      (__attribute__((address_space(3))) void*)l, 16, 0, 0);
}
__device__ __forceinline__ void barrier_f() {
  asm volatile("" ::: "memory");
  __builtin_amdgcn_s_barrier();
  asm volatile("" ::: "memory");
}

// ---------------- merged weight transpose + f32->bf16 convert (1 launch) ----------------
__global__ __launch_bounds__(256) void wconv_all(
    const float* __restrict__ wq, const float* __restrict__ wk,
    const float* __restrict__ wv, const float* __restrict__ wo,
    const float* __restrict__ wg, const float* __restrict__ wu,
    const float* __restrict__ wd,
    u16* wq_t, u16* wk_t, u16* wv_t, u16* wo_t,
    u16* wg_t, u16* wu_t, u16* wd_t) {
  __shared__ float tile[64][65];
  const int t = blockIdx.x;
  const float* in; u16* out; int Kd, Nd, lt;
  if (t < 4096) {
    const int m = t >> 10; lt = t & 1023;
    in  = m == 0 ? wq   : m == 1 ? wk   : m == 2 ? wv   : wo;
    out = m == 0 ? wq_t : m == 1 ? wk_t : m == 2 ? wv_t : wo_t;
    Kd = 2048; Nd = 2048;
  } else if (t < 12288) {
    const int m = (t - 4096) >> 12; lt = (t - 4096) & 4095;
    in = m == 0 ? wg : wu; out = m == 0 ? wg_t : wu_t;
    Kd = 2048; Nd = 8192;
  } else {
    lt = t - 12288; in = wd; out = wd_t; Kd = 8192; Nd = 2048;
  }
  const int ntx = Nd >> 6;
  const int n0 = (lt % ntx) * 64, k0 = (lt / ntx) * 64;
  const int tid = threadIdx.x;
  const int r = tid >> 4, c4 = (tid & 15) * 4;
#pragma unroll
  for (int rr = 0; rr < 4; ++rr) {
    int kr = rr * 16 + r;
    float4 v = *(const float4*)&in[(size_t)(k0 + kr) * Nd + n0 + c4];
    tile[kr][c4 + 0] = v.x; tile[kr][c4 + 1] = v.y;
    tile[kr][c4 + 2] = v.z; tile[kr][c4 + 3] = v.w;
  }
  __syncthreads();
#pragma unroll
  for (int rr = 0; rr < 4; ++rr) {
    int nr = rr * 16 + r;
    uint2 o;
    o.x = (unsigned)f2bf(tile[c4 + 0][nr]) | ((unsigned)f2bf(tile[c4 + 1][nr]) << 16);
    o.y = (unsigned)f2bf(tile[c4 + 2][nr]) | ((unsigned)f2bf(tile[c4 + 3][nr]) << 16);
    *(uint2*)&out[(size_t)(n0 + nr) * Kd + k0 + c4] = o;
  }
}

// ---------------- RMSNorm: f32 in -> bf16 out ----------------
__global__ __launch_bounds__(256) void rmsnorm_kernel(
    const float* __restrict__ in, const float* __restrict__ wt, u16* __restrict__ out) {
  const int row = blockIdx.x;
  const int tid = threadIdx.x;
  const float* rp = in + (size_t)row * D_MODEL;
  float4 a = *(const float4*)&rp[tid * 8];
  float4 b = *(const float4*)&rp[tid * 8 + 4];
  float ss = a.x*a.x + a.y*a.y + a.z*a.z + a.w*a.w
           + b.x*b.x + b.y*b.y + b.z*b.z + b.w*b.w;
#pragma unroll
  for (int d = 1; d < 64; d <<= 1) ss += __shfl_xor(ss, d);
  __shared__ float red[4];
  if ((tid & 63) == 0) red[tid >> 6] = ss;
  __syncthreads();
  float tot = red[0] + red[1] + red[2] + red[3];
  float rms = rsqrtf(tot * (1.f / (float)D_MODEL) + 1e-6f);
  float4 wa = *(const float4*)&wt[tid * 8];
  float4 wb = *(const float4*)&wt[tid * 8 + 4];
  uint4 o;
  o.x = (unsigned)f2bf(a.x * rms * wa.x) | ((unsigned)f2bf(a.y * rms * wa.y) << 16);
  o.y = (unsigned)f2bf(a.z * rms * wa.z) | ((unsigned)f2bf(a.w * rms * wa.w) << 16);
  o.z = (unsigned)f2bf(b.x * rms * wb.x) | ((unsigned)f2bf(b.y * rms * wb.y) << 16);
  o.w = (unsigned)f2bf(b.z * rms * wb.z) | ((unsigned)f2bf(b.w * rms * wb.w) << 16);
  *(uint4*)&out[(size_t)row * D_MODEL + tid * 8] = o;
}

// ---------------- staging: RN rows x 64 K into region (swizzled source) ----------------
template <int RN>
__device__ __forceinline__ void stage_op(const u16* src, int ldE,
                                         int row0, int ktbyte, u16* slot,
                                         int w, int lane) {
  constexpr int L = RN / 64;
#pragma unroll
  for (int l = 0; l < L; ++l) {
    const int dst = l * 8192 + w * 1024;
    const int dl = dst + lane * 16;
    const int srcb = dl ^ (((dl >> 7) & 7) << 4);
    const int row = srcb >> 7, colb = srcb & 127;
    gload_lds16((const char*)src + (size_t)(row0 + row) * ldE * 2 + ktbyte + colb,
                (char*)slot + dst);
  }
}

// ---------------- fused QKV GEMM: triple-B (BN=64) sharing one A staging ----------------
__global__ __launch_bounds__(512, 1) void gemm_qkv(
    const u16* __restrict__ A, const u16* __restrict__ Bq,
    const u16* __restrict__ Bk, const u16* __restrict__ Bv,
    int M, int N, int K,
    u16* __restrict__ oq, u16* __restrict__ ok, u16* __restrict__ ovt,
    const float* __restrict__ fc, const float* __restrict__ fs) {
  extern __shared__ u16 smem[];
  const int tid = threadIdx.x;
  const int w = tid >> 6, lane = tid & 63;
  const int nwg = gridDim.x, bid = blockIdx.x;
  const int sw = (bid & 7) * (nwg >> 3) + (bid >> 3);
  const int mtiles = M / 256;
  const int m0 = (sw % mtiles) * 256;
  const int n0 = (sw / mtiles) * 64;
  const int wm = w >> 1, wn = w & 1;
  const int KT = K / 64;
  const int ql = lane & 15, qh = (lane >> 4) * 16;
  f32x4 aq[4][2] = {}, ak[4][2] = {}, av[4][2] = {};

  auto stage = [&](int t, int slot) {
    u16* base = smem + slot * QKV_SLOT_U16;
    const int kb = t * 128;
    stage_op<256>(A,  K, m0, kb, base,          w, lane);
    stage_op<64>(Bq, K, n0, kb, base + 16384, w, lane);
    stage_op<64>(Bk, K, n0, kb, base + 20480, w, lane);
    stage_op<64>(Bv, K, n0, kb, base + 24576, w, lane);
  };

  stage(0, 0);
  for (int t = 0; t < KT; ++t) {
    if (t + 1 < KT) {
      stage(t + 1, (t + 1) & 1);
      asm volatile("s_waitcnt vmcnt(7)" ::: "memory");
    } else {
      asm volatile("s_waitcnt vmcnt(0)" ::: "memory");
    }
    __builtin_amdgcn_s_barrier();
    asm volatile("" ::: "memory");

    const u16* sA = smem + (t & 1) * QKV_SLOT_U16;
    const u16* sQ = sA + 16384;
    const u16* sK = sA + 20480;
    const u16* sV = sA + 24576;
#pragma unroll
    for (int kk = 0; kk < 2; ++kk) {
      bf16x8 af[4], bq[2], bk[2], bv[2];
      const int cb = kk * 64 + qh;
#pragma unroll
      for (int i = 0; i < 4; ++i) {
        const int row = wm * 64 + i * 16 + ql;
        af[i] = *(const bf16x8*)((const char*)sA + (((row << 7) + cb) ^ ((row & 7) << 4)));
      }
#pragma unroll
      for (int j = 0; j < 2; ++j) {
        const int row = wn * 32 + j * 16 + ql;
        const int byt = (((row << 7) + cb) ^ ((row & 7) << 4));
        bq[j] = *(const bf16x8*)((const char*)sQ + byt);
        bk[j] = *(const bf16x8*)((const char*)sK + byt);
        bv[j] = *(const bf16x8*)((const char*)sV + byt);
      }
      __builtin_amdgcn_s_setprio(1);
#pragma unroll
      for (int i = 0; i < 4; ++i)
#pragma unroll
        for (int j = 0; j < 2; ++j) {
          aq[i][j] = __builtin_amdgcn_mfma_f32_16x16x32_bf16(af[i], bq[j], aq[i][j], 0, 0, 0);
          ak[i][j] = __builtin_amdgcn_mfma_f32_16x16x32_bf16(af[i], bk[j], ak[i][j], 0, 0, 0);
          av[i][j] = __builtin_amdgcn_mfma_f32_16x16x32_bf16(af[i], bv[j], av[i][j], 0, 0, 0);
        }
      __builtin_amdgcn_s_setprio(0);
    }
    __builtin_amdgcn_s_barrier();
    asm volatile("" ::: "memory");
  }

  const int rbase = (lane >> 4) * 4;
#pragma unroll
  for (int i = 0; i < 4; ++i) {
#pragma unroll
    for (int j = 0; j < 2; ++j) {
      const int grow0 = m0 + wm * 64 + i * 16 + rbase;
      const int c = n0 + wn * 32 + j * 16 + ql;
      const int i2 = (c & 63) >> 1;
      const int odd = c & 1;
      {
        const int b = grow0 >> 11, s4 = grow0 & (S_LEN - 1);
        const int h = c >> 6, dh = c & 63;
        uint2 ov;
        ov.x = (unsigned)f2bf(av[i][j][0]) | ((unsigned)f2bf(av[i][j][1]) << 16);
        ov.y = (unsigned)f2bf(av[i][j][2]) | ((unsigned)f2bf(av[i][j][3]) << 16);
        *(uint2*)&ovt[((((size_t)b * NHEAD + h) * DHEAD + dh) << 11) + s4] = ov;
      }
#pragma unroll
      for (int r = 0; r < 4; ++r) {
        const int grow = grow0 + r;
        const int s4 = grow & (S_LEN - 1);
        const float cs = fc[s4 * 32 + i2], sn = fs[s4 * 32 + i2];
        {
          const float v = aq[i][j][r];
          const float p = __shfl_xor(v, 1);
          const float outv = odd ? (p * sn + v * cs) : (v * cs - p * sn);
          oq[(size_t)grow * D_MODEL + c] = f2bf(outv);
        }
        {
          const float v = ak[i][j][r];
          const float p = __shfl_xor(v, 1);
          const float outv = odd ? (p * sn + v * cs) : (v * cs - p * sn);
          ok[(size_t)grow * D_MODEL + c] = f2bf(outv);
        }
      }
    }
  }
}

// ---------------- fused gate+up GEMM: 4-phase pipelined (T3+T4), ring-2 ----------------
__global__ __launch_bounds__(512, 1) void gemm_gu(
    const u16* __restrict__ A, const u16* __restrict__ Bg, const u16* __restrict__ Bu,
    int M, int N, int K, u16* __restrict__ o0) {
  extern __shared__ u16 smem[];
  const int tid = threadIdx.x;
  const int w = tid >> 6, lane = tid & 63;
  const int nwg = gridDim.x, bid = blockIdx.x;
  const int sw = (bid & 7) * (nwg >> 3) + (bid >> 3);
  const int mtiles = M / 256;
  const int m0 = (sw % mtiles) * 256;
  const int n0 = (sw / mtiles) * 128;
  const int wm = w >> 1, wn = w & 1;
  const int KT = K / 64;
  const int ql = lane & 15, qh = (lane >> 4) * 16;
  f32x4 accg[4][4] = {}, accu[4][4] = {};

  int abyt[4][2], bbyt[4][2];
#pragma unroll
  for (int i = 0; i < 4; ++i)
#pragma unroll
    for (int kk = 0; kk < 2; ++kk) {
      const int ra = wm * 64 + i * 16 + ql;
      abyt[i][kk] = ((ra << 7) + kk * 64 + qh) ^ ((ra & 7) << 4);
      const int rb = wn * 64 + i * 16 + ql;
      bbyt[i][kk] = ((rb << 7) + kk * 64 + qh) ^ ((rb & 7) << 4);
    }

  auto stage_E = [&](int t, int slot) {
    u16* base = smem + slot * 32768;
    stage_op<256>(A,  K, m0, t * 128, base,         w, lane);
    stage_op<128>(Bg, K, n0, t * 128, base + 16384, w, lane);
  };
  auto stage_L = [&](int t, int slot) {
    u16* base = smem + slot * 32768;
    stage_op<128>(Bu, K, n0, t * 128, base + 24576, w, lane);
  };

  stage_E(0, 0);
  stage_L(0, 0);
  asm volatile("s_waitcnt vmcnt(2)" ::: "memory");
  barrier_f();

  for (int t = 0; t < KT; ++t) {
    const bool last = (t == KT - 1);
    const char* sA = (const char*)smem + (t & 1) * 65536;
    const char* sG = sA + 32768;
    const char* sU = sA + 49152;
    bf16x8 af[4], bb[4];
#pragma unroll
    for (int i = 0; i < 4; ++i) af[i] = *(const bf16x8*)(sA + abyt[i][0]);
#pragma unroll
    for (int j = 0; j < 4; ++j) bb[j] = *(const bf16x8*)(sG + bbyt[j][0]);
    if (!last) {
      stage_E(t + 1, (t + 1) & 1);
      asm volatile("s_waitcnt vmcnt(6)" ::: "memory");
    } else {
      asm volatile("s_waitcnt vmcnt(0)" ::: "memory");
    }
    barrier_f();
    __builtin_amdgcn_s_setprio(1);
#pragma unroll
    for (int i = 0; i < 4; ++i)
#pragma unroll
      for (int j = 0; j < 4; ++j)
        accg[i][j] = __builtin_amdgcn_mfma_f32_16x16x32_bf16(af[i], bb[j], accg[i][j], 0, 0, 0);
    __builtin_amdgcn_s_setprio(0);
    barrier_f();
#pragma unroll
    for (int j = 0; j < 4; ++j) bb[j] = *(const bf16x8*)(sU + bbyt[j][0]);
    if (!last) stage_L(t + 1, (t + 1) & 1);
    barrier_f();
    __builtin_amdgcn_s_setprio(1);
#pragma unroll
    for (int i = 0; i < 4; ++i)
#pragma unroll
      for (int j = 0; j < 4; ++j)
        accu[i][j] = __builtin_amdgcn_mfma_f32_16x16x32_bf16(af[i], bb[j], accu[i][j], 0, 0, 0);
    __builtin_amdgcn_s_setprio(0);
    barrier_f();
#pragma unroll
    for (int i = 0; i < 4; ++i) af[i] = *(const bf16x8*)(sA + abyt[i][1]);
#pragma unroll
    for (int j = 0; j < 4; ++j) bb[j] = *(const bf16x8*)(sG + bbyt[j][1]);
    barrier_f();
    __builtin_amdgcn_s_setprio(1);
#pragma unroll
    for (int i = 0; i < 4; ++i)
#pragma unroll
      for (int j = 0; j < 4; ++j)
        accg[i][j] = __builtin_amdgcn_mfma_f32_16x16x32_bf16(af[i], bb[j], accg[i][j], 0, 0, 0);
    __builtin_amdgcn_s_setprio(0);
    barrier_f();
#pragma unroll
    for (int j = 0; j < 4; ++j) bb[j] = *(const bf16x8*)(sU + bbyt[j][1]);
    if (!last) asm volatile("s_waitcnt vmcnt(2)" ::: "memory");
    barrier_f();
    __builtin_amdgcn_s_setprio(1);
#pragma unroll
    for (int i = 0; i < 4; ++i)
#pragma unroll
      for (int j = 0; j < 4; ++j)
        accu[i][j] = __builtin_amdgcn_mfma_f32_16x16x32_bf16(af[i], bb[j], accu[i][j], 0, 0, 0);
    __builtin_amdgcn_s_setprio(0);
    barrier_f();
  }

  const int rbase = (lane >> 4) * 4;
#pragma unroll
  for (int i = 0; i < 4; ++i) {
#pragma unroll
    for (int j = 0; j < 4; ++j) {
      const int grow0 = m0 + wm * 64 + i * 16 + rbase;
      const int gcol = n0 + wn * 64 + j * 16 + ql;
#pragma unroll
      for (int r = 0; r < 4; ++r) {
        const float g = accg[i][j][r];
        const float u = accu[i][j][r];
        const float sg = g / (1.f + __expf(-g));
        o0[(size_t)(grow0 + r) * N + gcol] = f2bf(sg * u);
      }
    }
  }
}

// ---------------- split-K GEMM: ring-2, 256x256, split-K=2, bf16 partials ----------------
// used for both down (Kld=8192) and O-proj (Kld=2048)
__global__ __launch_bounds__(512, 1) void gemm_dn(
    const u16* __restrict__ A, const u16* __restrict__ Bt,
    int M, int N, int Kld, u16* __restrict__ pbuf) {
  extern __shared__ u16 smem[];
  const int tid = threadIdx.x;
  const int w = tid >> 6, lane = tid & 63;
  const int nwg = gridDim.x, bid = blockIdx.x;
  const int sw = (bid & 7) * (nwg >> 3) + (bid >> 3);
  const int mtiles = M / 256;
  const int tilesPerSplit = mtiles * (N / 256);
  const int split = sw / tilesPerSplit;
  const int tt = sw % tilesPerSplit;
  const int m0 = (tt % mtiles) * 256;
  const int n0 = (tt / mtiles) * 256;
  const u16* Ap = A + (size_t)split * (Kld / 2);
  const u16* Bp = Bt + (size_t)split * (Kld / 2);
  u16* op = pbuf + (size_t)split * M * N;
  const int wm = w >> 2, wn = w & 3;
  const int KT = (Kld / 2) / 64;
  const int ql = lane & 15, qh = (lane >> 4) * 16;
  f32x4 acc[8][4] = {};

  auto stage = [&](int t, int slot) {
    u16* base = smem + slot * 32768;
    const int kb = t * 128;
    stage_op<256>(Ap, Kld, m0, kb, base,         w, lane);
    stage_op<256>(Bp, Kld, n0, kb, base + 16384, w, lane);
  };

  stage(0, 0);
  for (int t = 0; t < KT; ++t) {
    if (t + 1 < KT) {
      stage(t + 1, (t + 1) & 1);
      asm volatile("s_waitcnt vmcnt(8)" ::: "memory");
    } else {
      asm volatile("s_waitcnt vmcnt(0)" ::: "memory");
    }
    __builtin_amdgcn_s_barrier();
    asm volatile("" ::: "memory");

    const u16* sA = smem + (t & 1) * 32768;
    const u16* sB = sA + 16384;
#pragma unroll
    for (int kk = 0; kk < 2; ++kk) {
      bf16x8 af[8], bq[4];
      const int cb = kk * 64 + qh;
#pragma unroll
      for (int i = 0; i < 8; ++i) {
        const int row = wm * 128 + i * 16 + ql;
        af[i] = *(const bf16x8*)((const char*)sA + (((row << 7) + cb) ^ ((row & 7) << 4)));
      }
#pragma unroll
      for (int j = 0; j < 4; ++j) {
        const int row = wn * 64 + j * 16 + ql;
        bq[j] = *(const bf16x8*)((const char*)sB + (((row << 7) + cb) ^ ((row & 7) << 4)));
      }
      __builtin_amdgcn_s_setprio(1);
#pragma unroll
      for (int i = 0; i < 8; ++i)
#pragma unroll
        for (int j = 0; j < 4; ++j)
          acc[i][j] = __builtin_amdgcn_mfma_f32_16x16x32_bf16(af[i], bq[j], acc[i][j], 0, 0, 0);
      __builtin_amdgcn_s_setprio(0);
    }
    __builtin_amdgcn_s_barrier();
    asm volatile("" ::: "memory");
  }

  const int rbase = (lane >> 4) * 4;
#pragma unroll
  for (int i = 0; i < 8; ++i) {
#pragma unroll
    for (int j = 0; j < 4; ++j) {
      const int grow0 = m0 + wm * 128 + i * 16 + rbase;
      const int gcol = n0 + wn * 64 + j * 16 + ql;
#pragma unroll
      for (int r = 0; r < 4; ++r)
        op[(size_t)(grow0 + r) * N + gcol] = f2bf(acc[i][j][r]);
    }
  }
}

// ---------------- split-K combines (bf16 partials) ----------------
__global__ __launch_bounds__(256) void combine_kernel(
    const u16* __restrict__ p0, const u16* __restrict__ p1, float* __restrict__ out) {
  const size_t idx = ((size_t)blockIdx.x * 256 + threadIdx.x) * 8;
  bf16x8 a = *(const bf16x8*)&p0[idx];
  bf16x8 b = *(const bf16x8*)&p1[idx];
  float4 c0 = *(const float4*)&out[idx];
  float4 c1 = *(const float4*)&out[idx + 4];
  c0.x += bf2f((u16)a[0]) + bf2f((u16)b[0]);
  c0.y += bf2f((u16)a[1]) + bf2f((u16)b[1]);
  c0.z += bf2f((u16)a[2]) + bf2f((u16)b[2]);
  c0.w += bf2f((u16)a[3]) + bf2f((u16)b[3]);
  c1.x += bf2f((u16)a[4]) + bf2f((u16)b[4]);
  c1.y += bf2f((u16)a[5]) + bf2f((u16)b[5]);
  c1.z += bf2f((u16)a[6]) + bf2f((u16)b[6]);
  c1.w += bf2f((u16)a[7]) + bf2f((u16)b[7]);
  *(float4*)&out[idx] = c0;
  *(float4*)&out[idx + 4] = c1;
}

// out = x + p0 + p1 (O-proj + residual)
__global__ __launch_bounds__(256) void combine_o_kernel(
    const u16* __restrict__ p0, const u16* __restrict__ p1,
    const float* __restrict__ x, float* __restrict__ out) {
  const size_t idx = ((size_t)blockIdx.x * 256 + threadIdx.x) * 8;
  bf16x8 a = *(const bf16x8*)&p0[idx];
  bf16x8 b = *(const bf16x8*)&p1[idx];
  float4 x0 = *(const float4*)&x[idx];
  float4 x1 = *(const float4*)&x[idx + 4];
  float4 c0, c1;
  c0.x = x0.x + bf2f((u16)a[0]) + bf2f((u16)b[0]);
  c0.y = x0.y + bf2f((u16)a[1]) + bf2f((u16)b[1]);
  c0.z = x0.z + bf2f((u16)a[2]) + bf2f((u16)b[2]);
  c0.w = x0.w + bf2f((u16)a[3]) + bf2f((u16)b[3]);
  c1.x = x1.x + bf2f((u16)a[4]) + bf2f((u16)b[4]);
  c1.y = x1.y + bf2f((u16)a[5]) + bf2f((u16)b[5]);
  c1.z = x1.z + bf2f((u16)a[6]) + bf2f((u16)b[6]);
  c1.w = x1.w + bf2f((u16)a[7]) + bf2f((u16)b[7]);
  *(float4*)&out[idx] = c0;
  *(float4*)&out[idx + 4] = c1;
}

// ---------------- Flash attention (causal), swapped-QK^T, swizzled, ring-2 ----------------
__global__ __launch_bounds__(256) void attn_kernel(
    const u16* __restrict__ q, const u16* __restrict__ k,
    const u16* __restrict__ vt, u16* __restrict__ o) {
  __shared__ u16 lKV[2][128 * 64];
  __shared__ u16 lP[4][32 * 64];
  const int tid = threadIdx.x, w = tid >> 6, lane = tid & 63;
  const int ql = lane & 15, qh16 = (lane >> 4) * 16, rbase = (lane >> 4) * 4;
  const int bx = (int)gridDim.x - 1 - (int)blockIdx.x;
  const int bh = blockIdx.y, b = bh >> 5, h = bh & 31;
  const int q0 = bx * 128;
  const int nt = 2 * bx + 2;
  const char* kbase = (const char*)(k + ((size_t)b * S_LEN) * D_MODEL + h * DHEAD);
  const char* vbase = (const char*)(vt + (size_t)bh * DHEAD * S_LEN);

  bf16x8 qf[2][2];
#pragma unroll
  for (int i = 0; i < 2; ++i) {
    const size_t tok = (size_t)b * S_LEN + q0 + w * 32 + i * 16 + ql;
#pragma unroll
    for (int kk = 0; kk < 2; ++kk) {
      bf16x8 v = *(const bf16x8*)&q[tok * D_MODEL + h * DHEAD + kk * 32 + (lane >> 4) * 8];
#pragma unroll
      for (int e = 0; e < 8; ++e) v[e] = (short)f2bf(bf2f((u16)v[e]) * 0.125f);
      qf[i][kk] = v;
    }
  }

  float m[2] = {-1e30f, -1e30f}, l[2] = {0.f, 0.f};
  f32x4 oacc[2][4] = {};

  auto stage = [&](int kt, int slot) {
    const int s0 = kt * 64;
#pragma unroll
    for (int lo = 0; lo < 2; ++lo) {
      const int dst = lo * 4096 + w * 1024;
      const int dl = dst + lane * 16;
      const int srcb = dl ^ (((dl >> 7) & 7) << 4);
      const int row = srcb >> 7, colb = srcb & 127;
      gload_lds16(kbase + (size_t)(s0 + row) * (D_MODEL * 2) + colb,
                  (char*)&lKV[slot][0] + dst);
    }
#pragma unroll
    for (int lo = 0; lo < 2; ++lo) {
      const int dst = lo * 4096 + w * 1024;
      const int dl = dst + lane * 16;
      const int srcb = dl ^ (((dl >> 7) & 7) << 4);
      const int row = srcb >> 7, colb = srcb & 127;
      gload_lds16(vbase + (size_t)row * (S_LEN * 2) + (size_t)s0 * 2 + colb,
                  (char*)&lKV[slot][64 * 64] + dst);
    }
  };

  stage(0, 0);
  for (int kt = 0; kt < nt; ++kt) {
    if (kt + 1 < nt) {
      stage(kt + 1, (kt + 1) & 1);
      asm volatile("s_waitcnt vmcnt(4)" ::: "memory");
    } else {
      asm volatile("s_waitcnt vmcnt(0)" ::: "memory");
    }
    __builtin_amdgcn_s_barrier();
    asm volatile("" ::: "memory");

    const u16* sK = &lKV[kt & 1][0];
    const u16* sV = &lKV[kt & 1][64 * 64];
    const int s0 = kt * 64;

    f32x4 scT[2][4] = {};
#pragma unroll
    for (int kk = 0; kk < 2; ++kk) {
#pragma unroll
      for (int j = 0; j < 4; ++j) {
        const int row = j * 16 + ql;
        bf16x8 kf = *(const bf16x8*)((const char*)sK +
                      (((row << 7) + kk * 64 + qh16) ^ ((row & 7) << 4)));
#pragma unroll
        for (int i = 0; i < 2; ++i)
          scT[i][j] = __builtin_amdgcn_mfma_f32_16x16x32_bf16(kf, qf[i][kk], scT[i][j], 0, 0, 0);
      }
    }
    const bool diag = (s0 + 63 > q0);
#pragma unroll
    for (int i = 0; i < 2; ++i) {
      const int qrow = q0 + w * 32 + i * 16 + ql;
      if (diag) {
#pragma unroll
        for (int j = 0; j < 4; ++j)
#pragma unroll
          for (int r = 0; r < 4; ++r)
            if (s0 + j * 16 + rbase + r > qrow) scT[i][j][r] = -1e30f;
      }
      float mx = scT[i][0][0];
#pragma unroll
      for (int j = 0; j < 4; ++j)
#pragma unroll
        for (int r = 0; r < 4; ++r) mx = fmaxf(mx, scT[i][j][r]);
      mx = fmaxf(mx, __shfl_xor(mx, 16));
      mx = fmaxf(mx, __shfl_xor(mx, 32));
      const float mnew = fmaxf(m[i], mx);
      const float alpha = __expf(m[i] - mnew);
      m[i] = mnew;
      float rs = 0.f;
#pragma unroll
      for (int j = 0; j < 4; ++j)
#pragma unroll
        for (int r = 0; r < 4; ++r) {
          const float p = __expf(scT[i][j][r] - mnew);
          scT[i][j][r] = p;
          rs += p;
        }
      rs += __shfl_xor(rs, 16);
      rs += __shfl_xor(rs, 32);
      l[i] = l[i] * alpha + rs;
#pragma unroll
      for (int rr = 0; rr < 4; ++rr) {
        const float ar = __shfl(alpha, rbase + rr);
#pragma unroll
        for (int j = 0; j < 4; ++j) oacc[i][j][rr] *= ar;
      }
      const int prow = i * 16 + ql;
      const int pb = prow << 7;
      const int swz = (prow & 7) << 4;
#pragma unroll
      for (int j = 0; j < 4; ++j) {
#pragma unroll
        for (int rp = 0; rp < 2; ++rp) {
          const int col = j * 16 + rbase + rp * 2;
          unsigned pk = (unsigned)f2bf(scT[i][j][rp * 2]) |
                        ((unsigned)f2bf(scT[i][j][rp * 2 + 1]) << 16);
          *(unsigned*)((char*)lP[w] + ((pb + col * 2) ^ swz)) = pk;
        }
      }
    }
#pragma unroll
    for (int i = 0; i < 2; ++i) {
      const int arow = i * 16 + ql;
#pragma unroll
      for (int kk = 0; kk < 2; ++kk) {
        bf16x8 pa = *(const bf16x8*)((const char*)lP[w] +
                      (((arow << 7) + kk * 64 + qh16) ^ ((arow & 7) << 4)));
#pragma unroll
        for (int j = 0; j < 4; ++j) {
          const int vrow = j * 16 + ql;
          bf16x8 bv = *(const bf16x8*)((const char*)sV +
                        (((vrow << 7) + kk * 64 + qh16) ^ ((vrow & 7) << 4)));
          oacc[i][j] = __builtin_amdgcn_mfma_f32_16x16x32_bf16(pa, bv, oacc[i][j], 0, 0, 0);
        }
      }
    }
    __builtin_amdgcn_s_barrier();
    asm volatile("" ::: "memory");
  }
#pragma unroll
  for (int i = 0; i < 2; ++i) {
#pragma unroll
    for (int rr = 0; rr < 4; ++rr) {
      const float linv = 1.f / __shfl(l[i], rbase + rr);
      const size_t tok = (size_t)b * S_LEN + q0 + w * 32 + i * 16 + rbase + rr;
#pragma unroll
      for (int j = 0; j < 4; ++j)
        o[tok * D_MODEL + h * DHEAD + j * 16 + ql] = f2bf(oacc[i][j][rr] * linv);
    }
  }
}

// ---------------- host ----------------
extern "C" void kernel_launch(void* const* d_in, const int* in_sizes, int n_in,
                              void* d_out, int out_size, void* d_ws, size_t ws_size,
                              hipStream_t stream) {
  (void)in_sizes; (void)n_in; (void)out_size; (void)ws_size;
  const float* x  = (const float*)d_in[0];
  const float* fc = (const float*)d_in[1];
  const float* fs = (const float*)d_in[2];
  const float* wq = (const float*)d_in[4];
  const float* wk = (const float*)d_in[5];
  const float* wv = (const float*)d_in[6];
  const float* wo = (const float*)d_in[7];
  const float* wg = (const float*)d_in[8];
  const float* wu = (const float*)d_in[9];
  const float* wd = (const float*)d_in[10];
  const float* n1 = (const float*)d_in[11];
  const float* n2 = (const float*)d_in[12];
  float* out = (float*)d_out;

  char* ws = (char*)d_ws;
  size_t off = 0;
  auto alloc = [&](size_t bytes) { void* p = ws + off; off += (bytes + 255) & ~(size_t)255; return p; };
  u16* wq_t = (u16*)alloc((size_t)D_MODEL * D_MODEL * 2);
  u16* wk_t = (u16*)alloc((size_t)D_MODEL * D_MODEL * 2);
  u16* wv_t = (u16*)alloc((size_t)D_MODEL * D_MODEL * 2);
  u16* wo_t = (u16*)alloc((size_t)D_MODEL * D_MODEL * 2);
  u16* wg_t = (u16*)alloc((size_t)D_MODEL * FF_DIM * 2);
  u16* wu_t = (u16*)alloc((size_t)D_MODEL * FF_DIM * 2);
  u16* wd_t = (u16*)alloc((size_t)FF_DIM * D_MODEL * 2);
  u16* hn   = (u16*)alloc((size_t)NTOK * D_MODEL * 2);
  u16* qb   = (u16*)alloc((size_t)NTOK * D_MODEL * 2);
  u16* kb   = (u16*)alloc((size_t)NTOK * D_MODEL * 2);
  u16* vtb  = (u16*)alloc((size_t)NTOK * D_MODEL * 2);
  u16* ao   = (u16*)alloc((size_t)NTOK * D_MODEL * 2);
  u16* gt   = (u16*)alloc((size_t)NTOK * FF_DIM * 2);
  // bf16 split-K partials (2 x 16MB) reuse qb/kb after they are dead
  u16* pbuf = qb;

  wconv_all<<<16384, 256, 0, stream>>>(wq, wk, wv, wo, wg, wu, wd,
                                       wq_t, wk_t, wv_t, wo_t, wg_t, wu_t, wd_t);
  rmsnorm_kernel<<<NTOK, 256, 0, stream>>>(x, n1, hn);
  // fused QKV (triple-B BN=64, 112KB LDS): grid 512
  gemm_qkv<<<512, 512, QKV_LDS_BYTES, stream>>>(hn, wq_t, wk_t, wv_t,
                                                NTOK, D_MODEL, D_MODEL,
                                                qb, kb, vtb, fc, fs);
  attn_kernel<<<dim3(16, 64), 256, 0, stream>>>(qb, kb, vtb, ao);
  // O-proj: split-K=2 ring-2 (Kld=2048), bf16 partials into dead qb/kb; then out = x+p0+p1
  gemm_dn<<<256, 512, DN_LDS_BYTES, stream>>>(ao, wo_t, NTOK, D_MODEL, D_MODEL, pbuf);
  combine_o_kernel<<<(NTOK * D_MODEL) / (256 * 8), 256, 0, stream>>>(
      pbuf, pbuf + (size_t)NTOK * D_MODEL, x, out);
  rmsnorm_kernel<<<NTOK, 256, 0, stream>>>(out, n2, hn);
  gemm_gu<<<1024, 512, GU_LDS_BYTES, stream>>>(hn, wg_t, wu_t, NTOK, FF_DIM, D_MODEL, gt);
  // down: split-K=2 (Kld=8192), partials again into qb/kb region
  gemm_dn<<<256, 512, DN_LDS_BYTES, stream>>>(gt, wd_t, NTOK, D_MODEL, FF_DIM, pbuf);
  combine_kernel<<<(NTOK * D_MODEL) / (256 * 8), 256, 0, stream>>>(
      pbuf, pbuf + (size_t)NTOK * D_MODEL, out);
}

// Round 15
// 773.050 us; speedup vs baseline: 1.0585x; 1.0325x over previous
//
#include <hip/hip_runtime.h>

typedef unsigned short u16;
typedef __attribute__((ext_vector_type(8))) short bf16x8;
typedef __attribute__((ext_vector_type(4))) float f32x4;

#define S_LEN 2048
#define D_MODEL 2048
#define NHEAD 32
#define DHEAD 64
#define FF_DIM 8192
#define NTOK 4096

#define GU_LDS_BYTES (2 * 65536)              // 128KB
#define DN_LDS_BYTES (2 * 65536)              // 128KB
#define QKV_SLOT_U16 (16384 + 3 * 4096)       // 28672 u16 = 56KB
#define QKV_LDS_BYTES (2 * QKV_SLOT_U16 * 2)  // 112KB

__device__ __forceinline__ u16 f2bf(float f) {
  union { float f; unsigned u; } v; v.f = f;
  unsigned r = v.u + 0x7fffu + ((v.u >> 16) & 1u);
  return (u16)(r >> 16);
}
__device__ __forceinline__ float bf2f(u16 b) {
  union { unsigned u; float f; } v; v.u = ((unsigned)b) << 16;
  return v.f;
}
__device__ __forceinline__ void gload_lds16(const void* g, void* l) {
  __builtin_amdgcn_global_load_lds(
      (const __attribute__((address_space(1))) void*)g,
      (__attribute__((address_space(3))) void*)l, 16, 0, 0);
}
__device__ __forceinline__ void barrier_f() {
  asm volatile("" ::: "memory");
  __builtin_amdgcn_s_barrier();
  asm volatile("" ::: "memory");
}

// ---------------- merged weight transpose + f32->bf16 convert (1 launch) ----------------
__global__ __launch_bounds__(256) void wconv_all(
    const float* __restrict__ wq, const float* __restrict__ wk,
    const float* __restrict__ wv, const float* __restrict__ wo,
    const float* __restrict__ wg, const float* __restrict__ wu,
    const float* __restrict__ wd,
    u16* wq_t, u16* wk_t, u16* wv_t, u16* wo_t,
    u16* wg_t, u16* wu_t, u16* wd_t) {
  __shared__ float tile[64][65];
  const int t = blockIdx.x;
  const float* in; u16* out; int Kd, Nd, lt;
  if (t < 4096) {
    const int m = t >> 10; lt = t & 1023;
    in  = m == 0 ? wq   : m == 1 ? wk   : m == 2 ? wv   : wo;
    out = m == 0 ? wq_t : m == 1 ? wk_t : m == 2 ? wv_t : wo_t;
    Kd = 2048; Nd = 2048;
  } else if (t < 12288) {
    const int m = (t - 4096) >> 12; lt = (t - 4096) & 4095;
    in = m == 0 ? wg : wu; out = m == 0 ? wg_t : wu_t;
    Kd = 2048; Nd = 8192;
  } else {
    lt = t - 12288; in = wd; out = wd_t; Kd = 8192; Nd = 2048;
  }
  const int ntx = Nd >> 6;
  const int n0 = (lt % ntx) * 64, k0 = (lt / ntx) * 64;
  const int tid = threadIdx.x;
  const int r = tid >> 4, c4 = (tid & 15) * 4;
#pragma unroll
  for (int rr = 0; rr < 4; ++rr) {
    int kr = rr * 16 + r;
    float4 v = *(const float4*)&in[(size_t)(k0 + kr) * Nd + n0 + c4];
    tile[kr][c4 + 0] = v.x; tile[kr][c4 + 1] = v.y;
    tile[kr][c4 + 2] = v.z; tile[kr][c4 + 3] = v.w;
  }
  __syncthreads();
#pragma unroll
  for (int rr = 0; rr < 4; ++rr) {
    int nr = rr * 16 + r;
    uint2 o;
    o.x = (unsigned)f2bf(tile[c4 + 0][nr]) | ((unsigned)f2bf(tile[c4 + 1][nr]) << 16);
    o.y = (unsigned)f2bf(tile[c4 + 2][nr]) | ((unsigned)f2bf(tile[c4 + 3][nr]) << 16);
    *(uint2*)&out[(size_t)(n0 + nr) * Kd + k0 + c4] = o;
  }
}

// ---------------- RMSNorm: f32 in -> bf16 out (used for norm1 only) ----------------
__global__ __launch_bounds__(256) void rmsnorm_kernel(
    const float* __restrict__ in, const float* __restrict__ wt, u16* __restrict__ out) {
  const int row = blockIdx.x;
  const int tid = threadIdx.x;
  const float* rp = in + (size_t)row * D_MODEL;
  float4 a = *(const float4*)&rp[tid * 8];
  float4 b = *(const float4*)&rp[tid * 8 + 4];
  float ss = a.x*a.x + a.y*a.y + a.z*a.z + a.w*a.w
           + b.x*b.x + b.y*b.y + b.z*b.z + b.w*b.w;
#pragma unroll
  for (int d = 1; d < 64; d <<= 1) ss += __shfl_xor(ss, d);
  __shared__ float red[4];
  if ((tid & 63) == 0) red[tid >> 6] = ss;
  __syncthreads();
  float tot = red[0] + red[1] + red[2] + red[3];
  float rms = rsqrtf(tot * (1.f / (float)D_MODEL) + 1e-6f);
  float4 wa = *(const float4*)&wt[tid * 8];
  float4 wb = *(const float4*)&wt[tid * 8 + 4];
  uint4 o;
  o.x = (unsigned)f2bf(a.x * rms * wa.x) | ((unsigned)f2bf(a.y * rms * wa.y) << 16);
  o.y = (unsigned)f2bf(a.z * rms * wa.z) | ((unsigned)f2bf(a.w * rms * wa.w) << 16);
  o.z = (unsigned)f2bf(b.x * rms * wb.x) | ((unsigned)f2bf(b.y * rms * wb.y) << 16);
  o.w = (unsigned)f2bf(b.z * rms * wb.z) | ((unsigned)f2bf(b.w * rms * wb.w) << 16);
  *(uint4*)&out[(size_t)row * D_MODEL + tid * 8] = o;
}

// ---------------- staging: RN rows x 64 K into region (swizzled source) ----------------
template <int RN>
__device__ __forceinline__ void stage_op(const u16* src, int ldE,
                                         int row0, int ktbyte, u16* slot,
                                         int w, int lane) {
  constexpr int L = RN / 64;
#pragma unroll
  for (int l = 0; l < L; ++l) {
    const int dst = l * 8192 + w * 1024;
    const int dl = dst + lane * 16;
    const int srcb = dl ^ (((dl >> 7) & 7) << 4);
    const int row = srcb >> 7, colb = srcb & 127;
    gload_lds16((const char*)src + (size_t)(row0 + row) * ldE * 2 + ktbyte + colb,
                (char*)slot + dst);
  }
}

// ---------------- fused QKV GEMM: triple-B (BN=64) sharing one A staging ----------------
__global__ __launch_bounds__(512, 1) void gemm_qkv(
    const u16* __restrict__ A, const u16* __restrict__ Bq,
    const u16* __restrict__ Bk, const u16* __restrict__ Bv,
    int M, int N, int K,
    u16* __restrict__ oq, u16* __restrict__ ok, u16* __restrict__ ovt,
    const float* __restrict__ fc, const float* __restrict__ fs) {
  extern __shared__ u16 smem[];
  const int tid = threadIdx.x;
  const int w = tid >> 6, lane = tid & 63;
  const int nwg = gridDim.x, bid = blockIdx.x;
  const int sw = (bid & 7) * (nwg >> 3) + (bid >> 3);
  const int mtiles = M / 256;
  const int m0 = (sw % mtiles) * 256;
  const int n0 = (sw / mtiles) * 64;
  const int wm = w >> 1, wn = w & 1;
  const int KT = K / 64;
  const int ql = lane & 15, qh = (lane >> 4) * 16;
  f32x4 aq[4][2] = {}, ak[4][2] = {}, av[4][2] = {};

  auto stage = [&](int t, int slot) {
    u16* base = smem + slot * QKV_SLOT_U16;
    const int kb = t * 128;
    stage_op<256>(A,  K, m0, kb, base,          w, lane);
    stage_op<64>(Bq, K, n0, kb, base + 16384, w, lane);
    stage_op<64>(Bk, K, n0, kb, base + 20480, w, lane);
    stage_op<64>(Bv, K, n0, kb, base + 24576, w, lane);
  };

  stage(0, 0);
  for (int t = 0; t < KT; ++t) {
    if (t + 1 < KT) {
      stage(t + 1, (t + 1) & 1);
      asm volatile("s_waitcnt vmcnt(7)" ::: "memory");
    } else {
      asm volatile("s_waitcnt vmcnt(0)" ::: "memory");
    }
    __builtin_amdgcn_s_barrier();
    asm volatile("" ::: "memory");

    const u16* sA = smem + (t & 1) * QKV_SLOT_U16;
    const u16* sQ = sA + 16384;
    const u16* sK = sA + 20480;
    const u16* sV = sA + 24576;
#pragma unroll
    for (int kk = 0; kk < 2; ++kk) {
      bf16x8 af[4], bq[2], bk[2], bv[2];
      const int cb = kk * 64 + qh;
#pragma unroll
      for (int i = 0; i < 4; ++i) {
        const int row = wm * 64 + i * 16 + ql;
        af[i] = *(const bf16x8*)((const char*)sA + (((row << 7) + cb) ^ ((row & 7) << 4)));
      }
#pragma unroll
      for (int j = 0; j < 2; ++j) {
        const int row = wn * 32 + j * 16 + ql;
        const int byt = (((row << 7) + cb) ^ ((row & 7) << 4));
        bq[j] = *(const bf16x8*)((const char*)sQ + byt);
        bk[j] = *(const bf16x8*)((const char*)sK + byt);
        bv[j] = *(const bf16x8*)((const char*)sV + byt);
      }
      __builtin_amdgcn_s_setprio(1);
#pragma unroll
      for (int i = 0; i < 4; ++i)
#pragma unroll
        for (int j = 0; j < 2; ++j) {
          aq[i][j] = __builtin_amdgcn_mfma_f32_16x16x32_bf16(af[i], bq[j], aq[i][j], 0, 0, 0);
          ak[i][j] = __builtin_amdgcn_mfma_f32_16x16x32_bf16(af[i], bk[j], ak[i][j], 0, 0, 0);
          av[i][j] = __builtin_amdgcn_mfma_f32_16x16x32_bf16(af[i], bv[j], av[i][j], 0, 0, 0);
        }
      __builtin_amdgcn_s_setprio(0);
    }
    __builtin_amdgcn_s_barrier();
    asm volatile("" ::: "memory");
  }

  const int rbase = (lane >> 4) * 4;
#pragma unroll
  for (int i = 0; i < 4; ++i) {
#pragma unroll
    for (int j = 0; j < 2; ++j) {
      const int grow0 = m0 + wm * 64 + i * 16 + rbase;
      const int c = n0 + wn * 32 + j * 16 + ql;
      const int i2 = (c & 63) >> 1;
      const int odd = c & 1;
      {
        const int b = grow0 >> 11, s4 = grow0 & (S_LEN - 1);
        const int h = c >> 6, dh = c & 63;
        uint2 ov;
        ov.x = (unsigned)f2bf(av[i][j][0]) | ((unsigned)f2bf(av[i][j][1]) << 16);
        ov.y = (unsigned)f2bf(av[i][j][2]) | ((unsigned)f2bf(av[i][j][3]) << 16);
        *(uint2*)&ovt[((((size_t)b * NHEAD + h) * DHEAD + dh) << 11) + s4] = ov;
      }
#pragma unroll
      for (int r = 0; r < 4; ++r) {
        const int grow = grow0 + r;
        const int s4 = grow & (S_LEN - 1);
        const float cs = fc[s4 * 32 + i2], sn = fs[s4 * 32 + i2];
        {
          const float v = aq[i][j][r];
          const float p = __shfl_xor(v, 1);
          const float outv = odd ? (p * sn + v * cs) : (v * cs - p * sn);
          oq[(size_t)grow * D_MODEL + c] = f2bf(outv);
        }
        {
          const float v = ak[i][j][r];
          const float p = __shfl_xor(v, 1);
          const float outv = odd ? (p * sn + v * cs) : (v * cs - p * sn);
          ok[(size_t)grow * D_MODEL + c] = f2bf(outv);
        }
      }
    }
  }
}

// ---------------- fused gate+up GEMM: 4-phase pipelined (T3+T4), ring-2 ----------------
__global__ __launch_bounds__(512, 1) void gemm_gu(
    const u16* __restrict__ A, const u16* __restrict__ Bg, const u16* __restrict__ Bu,
    int M, int N, int K, u16* __restrict__ o0) {
  extern __shared__ u16 smem[];
  const int tid = threadIdx.x;
  const int w = tid >> 6, lane = tid & 63;
  const int nwg = gridDim.x, bid = blockIdx.x;
  const int sw = (bid & 7) * (nwg >> 3) + (bid >> 3);
  const int mtiles = M / 256;
  const int m0 = (sw % mtiles) * 256;
  const int n0 = (sw / mtiles) * 128;
  const int wm = w >> 1, wn = w & 1;
  const int KT = K / 64;
  const int ql = lane & 15, qh = (lane >> 4) * 16;
  f32x4 accg[4][4] = {}, accu[4][4] = {};

  int abyt[4][2], bbyt[4][2];
#pragma unroll
  for (int i = 0; i < 4; ++i)
#pragma unroll
    for (int kk = 0; kk < 2; ++kk) {
      const int ra = wm * 64 + i * 16 + ql;
      abyt[i][kk] = ((ra << 7) + kk * 64 + qh) ^ ((ra & 7) << 4);
      const int rb = wn * 64 + i * 16 + ql;
      bbyt[i][kk] = ((rb << 7) + kk * 64 + qh) ^ ((rb & 7) << 4);
    }

  auto stage_E = [&](int t, int slot) {
    u16* base = smem + slot * 32768;
    stage_op<256>(A,  K, m0, t * 128, base,         w, lane);
    stage_op<128>(Bg, K, n0, t * 128, base + 16384, w, lane);
  };
  auto stage_L = [&](int t, int slot) {
    u16* base = smem + slot * 32768;
    stage_op<128>(Bu, K, n0, t * 128, base + 24576, w, lane);
  };

  stage_E(0, 0);
  stage_L(0, 0);
  asm volatile("s_waitcnt vmcnt(2)" ::: "memory");
  barrier_f();

  for (int t = 0; t < KT; ++t) {
    const bool last = (t == KT - 1);
    const char* sA = (const char*)smem + (t & 1) * 65536;
    const char* sG = sA + 32768;
    const char* sU = sA + 49152;
    bf16x8 af[4], bb[4];
#pragma unroll
    for (int i = 0; i < 4; ++i) af[i] = *(const bf16x8*)(sA + abyt[i][0]);
#pragma unroll
    for (int j = 0; j < 4; ++j) bb[j] = *(const bf16x8*)(sG + bbyt[j][0]);
    if (!last) {
      stage_E(t + 1, (t + 1) & 1);
      asm volatile("s_waitcnt vmcnt(6)" ::: "memory");
    } else {
      asm volatile("s_waitcnt vmcnt(0)" ::: "memory");
    }
    barrier_f();
    __builtin_amdgcn_s_setprio(1);
#pragma unroll
    for (int i = 0; i < 4; ++i)
#pragma unroll
      for (int j = 0; j < 4; ++j)
        accg[i][j] = __builtin_amdgcn_mfma_f32_16x16x32_bf16(af[i], bb[j], accg[i][j], 0, 0, 0);
    __builtin_amdgcn_s_setprio(0);
    barrier_f();
#pragma unroll
    for (int j = 0; j < 4; ++j) bb[j] = *(const bf16x8*)(sU + bbyt[j][0]);
    if (!last) stage_L(t + 1, (t + 1) & 1);
    barrier_f();
    __builtin_amdgcn_s_setprio(1);
#pragma unroll
    for (int i = 0; i < 4; ++i)
#pragma unroll
      for (int j = 0; j < 4; ++j)
        accu[i][j] = __builtin_amdgcn_mfma_f32_16x16x32_bf16(af[i], bb[j], accu[i][j], 0, 0, 0);
    __builtin_amdgcn_s_setprio(0);
    barrier_f();
#pragma unroll
    for (int i = 0; i < 4; ++i) af[i] = *(const bf16x8*)(sA + abyt[i][1]);
#pragma unroll
    for (int j = 0; j < 4; ++j) bb[j] = *(const bf16x8*)(sG + bbyt[j][1]);
    barrier_f();
    __builtin_amdgcn_s_setprio(1);
#pragma unroll
    for (int i = 0; i < 4; ++i)
#pragma unroll
      for (int j = 0; j < 4; ++j)
        accg[i][j] = __builtin_amdgcn_mfma_f32_16x16x32_bf16(af[i], bb[j], accg[i][j], 0, 0, 0);
    __builtin_amdgcn_s_setprio(0);
    barrier_f();
#pragma unroll
    for (int j = 0; j < 4; ++j) bb[j] = *(const bf16x8*)(sU + bbyt[j][1]);
    if (!last) asm volatile("s_waitcnt vmcnt(2)" ::: "memory");
    barrier_f();
    __builtin_amdgcn_s_setprio(1);
#pragma unroll
    for (int i = 0; i < 4; ++i)
#pragma unroll
      for (int j = 0; j < 4; ++j)
        accu[i][j] = __builtin_amdgcn_mfma_f32_16x16x32_bf16(af[i], bb[j], accu[i][j], 0, 0, 0);
    __builtin_amdgcn_s_setprio(0);
    barrier_f();
  }

  const int rbase = (lane >> 4) * 4;
#pragma unroll
  for (int i = 0; i < 4; ++i) {
#pragma unroll
    for (int j = 0; j < 4; ++j) {
      const int grow0 = m0 + wm * 64 + i * 16 + rbase;
      const int gcol = n0 + wn * 64 + j * 16 + ql;
#pragma unroll
      for (int r = 0; r < 4; ++r) {
        const float g = accg[i][j][r];
        const float u = accu[i][j][r];
        const float sg = g / (1.f + __expf(-g));
        o0[(size_t)(grow0 + r) * N + gcol] = f2bf(sg * u);
      }
    }
  }
}

// ---------------- split-K GEMM: ring-2, 256x256, split-K=2, bf16 partials ----------------
__global__ __launch_bounds__(512, 1) void gemm_dn(
    const u16* __restrict__ A, const u16* __restrict__ Bt,
    int M, int N, int Kld, u16* __restrict__ pbuf) {
  extern __shared__ u16 smem[];
  const int tid = threadIdx.x;
  const int w = tid >> 6, lane = tid & 63;
  const int nwg = gridDim.x, bid = blockIdx.x;
  const int sw = (bid & 7) * (nwg >> 3) + (bid >> 3);
  const int mtiles = M / 256;
  const int tilesPerSplit = mtiles * (N / 256);
  const int split = sw / tilesPerSplit;
  const int tt = sw % tilesPerSplit;
  const int m0 = (tt % mtiles) * 256;
  const int n0 = (tt / mtiles) * 256;
  const u16* Ap = A + (size_t)split * (Kld / 2);
  const u16* Bp = Bt + (size_t)split * (Kld / 2);
  u16* op = pbuf + (size_t)split * M * N;
  const int wm = w >> 2, wn = w & 3;
  const int KT = (Kld / 2) / 64;
  const int ql = lane & 15, qh = (lane >> 4) * 16;
  f32x4 acc[8][4] = {};

  auto stage = [&](int t, int slot) {
    u16* base = smem + slot * 32768;
    const int kb = t * 128;
    stage_op<256>(Ap, Kld, m0, kb, base,         w, lane);
    stage_op<256>(Bp, Kld, n0, kb, base + 16384, w, lane);
  };

  stage(0, 0);
  for (int t = 0; t < KT; ++t) {
    if (t + 1 < KT) {
      stage(t + 1, (t + 1) & 1);
      asm volatile("s_waitcnt vmcnt(8)" ::: "memory");
    } else {
      asm volatile("s_waitcnt vmcnt(0)" ::: "memory");
    }
    __builtin_amdgcn_s_barrier();
    asm volatile("" ::: "memory");

    const u16* sA = smem + (t & 1) * 32768;
    const u16* sB = sA + 16384;
#pragma unroll
    for (int kk = 0; kk < 2; ++kk) {
      bf16x8 af[8], bq[4];
      const int cb = kk * 64 + qh;
#pragma unroll
      for (int i = 0; i < 8; ++i) {
        const int row = wm * 128 + i * 16 + ql;
        af[i] = *(const bf16x8*)((const char*)sA + (((row << 7) + cb) ^ ((row & 7) << 4)));
      }
#pragma unroll
      for (int j = 0; j < 4; ++j) {
        const int row = wn * 64 + j * 16 + ql;
        bq[j] = *(const bf16x8*)((const char*)sB + (((row << 7) + cb) ^ ((row & 7) << 4)));
      }
      __builtin_amdgcn_s_setprio(1);
#pragma unroll
      for (int i = 0; i < 8; ++i)
#pragma unroll
        for (int j = 0; j < 4; ++j)
          acc[i][j] = __builtin_amdgcn_mfma_f32_16x16x32_bf16(af[i], bq[j], acc[i][j], 0, 0, 0);
      __builtin_amdgcn_s_setprio(0);
    }
    __builtin_amdgcn_s_barrier();
    asm volatile("" ::: "memory");
  }

  const int rbase = (lane >> 4) * 4;
#pragma unroll
  for (int i = 0; i < 8; ++i) {
#pragma unroll
    for (int j = 0; j < 4; ++j) {
      const int grow0 = m0 + wm * 128 + i * 16 + rbase;
      const int gcol = n0 + wn * 64 + j * 16 + ql;
#pragma unroll
      for (int r = 0; r < 4; ++r)
        op[(size_t)(grow0 + r) * N + gcol] = f2bf(acc[i][j][r]);
    }
  }
}

// ---------------- down combine: out += p0 + p1 (bf16 partials) ----------------
__global__ __launch_bounds__(256) void combine_kernel(
    const u16* __restrict__ p0, const u16* __restrict__ p1, float* __restrict__ out) {
  const size_t idx = ((size_t)blockIdx.x * 256 + threadIdx.x) * 8;
  bf16x8 a = *(const bf16x8*)&p0[idx];
  bf16x8 b = *(const bf16x8*)&p1[idx];
  float4 c0 = *(const float4*)&out[idx];
  float4 c1 = *(const float4*)&out[idx + 4];
  c0.x += bf2f((u16)a[0]) + bf2f((u16)b[0]);
  c0.y += bf2f((u16)a[1]) + bf2f((u16)b[1]);
  c0.z += bf2f((u16)a[2]) + bf2f((u16)b[2]);
  c0.w += bf2f((u16)a[3]) + bf2f((u16)b[3]);
  c1.x += bf2f((u16)a[4]) + bf2f((u16)b[4]);
  c1.y += bf2f((u16)a[5]) + bf2f((u16)b[5]);
  c1.z += bf2f((u16)a[6]) + bf2f((u16)b[6]);
  c1.w += bf2f((u16)a[7]) + bf2f((u16)b[7]);
  *(float4*)&out[idx] = c0;
  *(float4*)&out[idx + 4] = c1;
}

// ---------------- O-proj combine + residual + fused rmsnorm2 ----------------
// one block per row: out = x + p0 + p1 ; hn = rmsnorm(out) * n2w (bf16)
__global__ __launch_bounds__(256) void combine_o_norm(
    const u16* __restrict__ p0, const u16* __restrict__ p1,
    const float* __restrict__ x, const float* __restrict__ wt,
    float* __restrict__ out, u16* __restrict__ hn) {
  const int row = blockIdx.x;
  const int tid = threadIdx.x;
  const size_t base = (size_t)row * D_MODEL + tid * 8;
  bf16x8 a = *(const bf16x8*)&p0[base];
  bf16x8 b = *(const bf16x8*)&p1[base];
  float4 x0 = *(const float4*)&x[base];
  float4 x1 = *(const float4*)&x[base + 4];
  float c[8];
  c[0] = x0.x + bf2f((u16)a[0]) + bf2f((u16)b[0]);
  c[1] = x0.y + bf2f((u16)a[1]) + bf2f((u16)b[1]);
  c[2] = x0.z + bf2f((u16)a[2]) + bf2f((u16)b[2]);
  c[3] = x0.w + bf2f((u16)a[3]) + bf2f((u16)b[3]);
  c[4] = x1.x + bf2f((u16)a[4]) + bf2f((u16)b[4]);
  c[5] = x1.y + bf2f((u16)a[5]) + bf2f((u16)b[5]);
  c[6] = x1.z + bf2f((u16)a[6]) + bf2f((u16)b[6]);
  c[7] = x1.w + bf2f((u16)a[7]) + bf2f((u16)b[7]);
  float4 o0 = {c[0], c[1], c[2], c[3]};
  float4 o1 = {c[4], c[5], c[6], c[7]};
  *(float4*)&out[base] = o0;
  *(float4*)&out[base + 4] = o1;
  float ss = 0.f;
#pragma unroll
  for (int e = 0; e < 8; ++e) ss += c[e] * c[e];
#pragma unroll
  for (int d = 1; d < 64; d <<= 1) ss += __shfl_xor(ss, d);
  __shared__ float red[4];
  if ((tid & 63) == 0) red[tid >> 6] = ss;
  __syncthreads();
  const float tot = red[0] + red[1] + red[2] + red[3];
  const float rms = rsqrtf(tot * (1.f / (float)D_MODEL) + 1e-6f);
  float4 wa = *(const float4*)&wt[tid * 8];
  float4 wb = *(const float4*)&wt[tid * 8 + 4];
  uint4 o;
  o.x = (unsigned)f2bf(c[0] * rms * wa.x) | ((unsigned)f2bf(c[1] * rms * wa.y) << 16);
  o.y = (unsigned)f2bf(c[2] * rms * wa.z) | ((unsigned)f2bf(c[3] * rms * wa.w) << 16);
  o.z = (unsigned)f2bf(c[4] * rms * wb.x) | ((unsigned)f2bf(c[5] * rms * wb.y) << 16);
  o.w = (unsigned)f2bf(c[6] * rms * wb.z) | ((unsigned)f2bf(c[7] * rms * wb.w) << 16);
  *(uint4*)&hn[base] = o;
}

// ---------------- Flash attention (causal), swapped-QK^T, swizzled, ring-2, defer-max ----------------
__global__ __launch_bounds__(256) void attn_kernel(
    const u16* __restrict__ q, const u16* __restrict__ k,
    const u16* __restrict__ vt, u16* __restrict__ o) {
  __shared__ u16 lKV[2][128 * 64];
  __shared__ u16 lP[4][32 * 64];
  const int tid = threadIdx.x, w = tid >> 6, lane = tid & 63;
  const int ql = lane & 15, qh16 = (lane >> 4) * 16, rbase = (lane >> 4) * 4;
  const int bx = (int)gridDim.x - 1 - (int)blockIdx.x;
  const int bh = blockIdx.y, b = bh >> 5, h = bh & 31;
  const int q0 = bx * 128;
  const int nt = 2 * bx + 2;
  const char* kbase = (const char*)(k + ((size_t)b * S_LEN) * D_MODEL + h * DHEAD);
  const char* vbase = (const char*)(vt + (size_t)bh * DHEAD * S_LEN);

  bf16x8 qf[2][2];
#pragma unroll
  for (int i = 0; i < 2; ++i) {
    const size_t tok = (size_t)b * S_LEN + q0 + w * 32 + i * 16 + ql;
#pragma unroll
    for (int kk = 0; kk < 2; ++kk) {
      bf16x8 v = *(const bf16x8*)&q[tok * D_MODEL + h * DHEAD + kk * 32 + (lane >> 4) * 8];
#pragma unroll
      for (int e = 0; e < 8; ++e) v[e] = (short)f2bf(bf2f((u16)v[e]) * 0.125f);
      qf[i][kk] = v;
    }
  }

  float m[2] = {-1e30f, -1e30f}, l[2] = {0.f, 0.f};
  f32x4 oacc[2][4] = {};

  auto stage = [&](int kt, int slot) {
    const int s0 = kt * 64;
#pragma unroll
    for (int lo = 0; lo < 2; ++lo) {
      const int dst = lo * 4096 + w * 1024;
      const int dl = dst + lane * 16;
      const int srcb = dl ^ (((dl >> 7) & 7) << 4);
      const int row = srcb >> 7, colb = srcb & 127;
      gload_lds16(kbase + (size_t)(s0 + row) * (D_MODEL * 2) + colb,
                  (char*)&lKV[slot][0] + dst);
    }
#pragma unroll
    for (int lo = 0; lo < 2; ++lo) {
      const int dst = lo * 4096 + w * 1024;
      const int dl = dst + lane * 16;
      const int srcb = dl ^ (((dl >> 7) & 7) << 4);
      const int row = srcb >> 7, colb = srcb & 127;
      gload_lds16(vbase + (size_t)row * (S_LEN * 2) + (size_t)s0 * 2 + colb,
                  (char*)&lKV[slot][64 * 64] + dst);
    }
  };

  stage(0, 0);
  for (int kt = 0; kt < nt; ++kt) {
    if (kt + 1 < nt) {
      stage(kt + 1, (kt + 1) & 1);
      asm volatile("s_waitcnt vmcnt(4)" ::: "memory");
    } else {
      asm volatile("s_waitcnt vmcnt(0)" ::: "memory");
    }
    __builtin_amdgcn_s_barrier();
    asm volatile("" ::: "memory");

    const u16* sK = &lKV[kt & 1][0];
    const u16* sV = &lKV[kt & 1][64 * 64];
    const int s0 = kt * 64;

    f32x4 scT[2][4] = {};
#pragma unroll
    for (int kk = 0; kk < 2; ++kk) {
#pragma unroll
      for (int j = 0; j < 4; ++j) {
        const int row = j * 16 + ql;
        bf16x8 kf = *(const bf16x8*)((const char*)sK +
                      (((row << 7) + kk * 64 + qh16) ^ ((row & 7) << 4)));
#pragma unroll
        for (int i = 0; i < 2; ++i)
          scT[i][j] = __builtin_amdgcn_mfma_f32_16x16x32_bf16(kf, qf[i][kk], scT[i][j], 0, 0, 0);
      }
    }
    const bool diag = (s0 + 63 > q0);
#pragma unroll
    for (int i = 0; i < 2; ++i) {
      const int qrow = q0 + w * 32 + i * 16 + ql;
      if (diag) {
#pragma unroll
        for (int j = 0; j < 4; ++j)
#pragma unroll
          for (int r = 0; r < 4; ++r)
            if (s0 + j * 16 + rbase + r > qrow) scT[i][j][r] = -1e30f;
      }
      float mx = scT[i][0][0];
#pragma unroll
      for (int j = 0; j < 4; ++j)
#pragma unroll
        for (int r = 0; r < 4; ++r) mx = fmaxf(mx, scT[i][j][r]);
      mx = fmaxf(mx, __shfl_xor(mx, 16));
      mx = fmaxf(mx, __shfl_xor(mx, 32));
      // defer-max (T13): only rescale when the max grew by > 8
      float alpha = 1.f;
      if (!__all(mx - m[i] <= 8.f)) {
        const float mnew = fmaxf(m[i], mx);
        alpha = __expf(m[i] - mnew);
        m[i] = mnew;
#pragma unroll
        for (int rr = 0; rr < 4; ++rr) {
          const float ar = __shfl(alpha, rbase + rr);
#pragma unroll
          for (int j = 0; j < 4; ++j) oacc[i][j][rr] *= ar;
        }
      }
      float rs = 0.f;
#pragma unroll
      for (int j = 0; j < 4; ++j)
#pragma unroll
        for (int r = 0; r < 4; ++r) {
          const float p = __expf(scT[i][j][r] - m[i]);
          scT[i][j][r] = p;
          rs += p;
        }
      rs += __shfl_xor(rs, 16);
      rs += __shfl_xor(rs, 32);
      l[i] = l[i] * alpha + rs;
      const int prow = i * 16 + ql;
      const int pb = prow << 7;
      const int swz = (prow & 7) << 4;
#pragma unroll
      for (int j = 0; j < 4; ++j) {
#pragma unroll
        for (int rp = 0; rp < 2; ++rp) {
          const int col = j * 16 + rbase + rp * 2;
          unsigned pk = (unsigned)f2bf(scT[i][j][rp * 2]) |
                        ((unsigned)f2bf(scT[i][j][rp * 2 + 1]) << 16);
          *(unsigned*)((char*)lP[w] + ((pb + col * 2) ^ swz)) = pk;
        }
      }
    }
#pragma unroll
    for (int i = 0; i < 2; ++i) {
      const int arow = i * 16 + ql;
#pragma unroll
      for (int kk = 0; kk < 2; ++kk) {
        bf16x8 pa = *(const bf16x8*)((const char*)lP[w] +
                      (((arow << 7) + kk * 64 + qh16) ^ ((arow & 7) << 4)));
#pragma unroll
        for (int j = 0; j < 4; ++j) {
          const int vrow = j * 16 + ql;
          bf16x8 bv = *(const bf16x8*)((const char*)sV +
                        (((vrow << 7) + kk * 64 + qh16) ^ ((vrow & 7) << 4)));
          oacc[i][j] = __builtin_amdgcn_mfma_f32_16x16x32_bf16(pa, bv, oacc[i][j], 0, 0, 0);
        }
      }
    }
    __builtin_amdgcn_s_barrier();
    asm volatile("" ::: "memory");
  }
#pragma unroll
  for (int i = 0; i < 2; ++i) {
#pragma unroll
    for (int rr = 0; rr < 4; ++rr) {
      const float linv = 1.f / __shfl(l[i], rbase + rr);
      const size_t tok = (size_t)b * S_LEN + q0 + w * 32 + i * 16 + rbase + rr;
#pragma unroll
      for (int j = 0; j < 4; ++j)
        o[tok * D_MODEL + h * DHEAD + j * 16 + ql] = f2bf(oacc[i][j][rr] * linv);
    }
  }
}

// ---------------- host ----------------
extern "C" void kernel_launch(void* const* d_in, const int* in_sizes, int n_in,
                              void* d_out, int out_size, void* d_ws, size_t ws_size,
                              hipStream_t stream) {
  (void)in_sizes; (void)n_in; (void)out_size; (void)ws_size;
  const float* x  = (const float*)d_in[0];
  const float* fc = (const float*)d_in[1];
  const float* fs = (const float*)d_in[2];
  const float* wq = (const float*)d_in[4];
  const float* wk = (const float*)d_in[5];
  const float* wv = (const float*)d_in[6];
  const float* wo = (const float*)d_in[7];
  const float* wg = (const float*)d_in[8];
  const float* wu = (const float*)d_in[9];
  const float* wd = (const float*)d_in[10];
  const float* n1 = (const float*)d_in[11];
  const float* n2 = (const float*)d_in[12];
  float* out = (float*)d_out;

  char* ws = (char*)d_ws;
  size_t off = 0;
  auto alloc = [&](size_t bytes) { void* p = ws + off; off += (bytes + 255) & ~(size_t)255; return p; };
  u16* wq_t = (u16*)alloc((size_t)D_MODEL * D_MODEL * 2);
  u16* wk_t = (u16*)alloc((size_t)D_MODEL * D_MODEL * 2);
  u16* wv_t = (u16*)alloc((size_t)D_MODEL * D_MODEL * 2);
  u16* wo_t = (u16*)alloc((size_t)D_MODEL * D_MODEL * 2);
  u16* wg_t = (u16*)alloc((size_t)D_MODEL * FF_DIM * 2);
  u16* wu_t = (u16*)alloc((size_t)D_MODEL * FF_DIM * 2);
  u16* wd_t = (u16*)alloc((size_t)FF_DIM * D_MODEL * 2);
  u16* hn   = (u16*)alloc((size_t)NTOK * D_MODEL * 2);
  u16* qb   = (u16*)alloc((size_t)NTOK * D_MODEL * 2);
  u16* kb   = (u16*)alloc((size_t)NTOK * D_MODEL * 2);
  u16* vtb  = (u16*)alloc((size_t)NTOK * D_MODEL * 2);
  u16* ao   = (u16*)alloc((size_t)NTOK * D_MODEL * 2);
  u16* gt   = (u16*)alloc((size_t)NTOK * FF_DIM * 2);
  // bf16 split-K partials (2 x 16MB) reuse qb/kb after they are dead
  u16* pbuf = qb;

  wconv_all<<<16384, 256, 0, stream>>>(wq, wk, wv, wo, wg, wu, wd,
                                       wq_t, wk_t, wv_t, wo_t, wg_t, wu_t, wd_t);
  rmsnorm_kernel<<<NTOK, 256, 0, stream>>>(x, n1, hn);
  // fused QKV (triple-B BN=64, 112KB LDS): grid 512
  gemm_qkv<<<512, 512, QKV_LDS_BYTES, stream>>>(hn, wq_t, wk_t, wv_t,
                                                NTOK, D_MODEL, D_MODEL,
                                                qb, kb, vtb, fc, fs);
  attn_kernel<<<dim3(16, 64), 256, 0, stream>>>(qb, kb, vtb, ao);
  // O-proj: split-K=2 ring-2 (Kld=2048), bf16 partials into dead qb/kb
  gemm_dn<<<256, 512, DN_LDS_BYTES, stream>>>(ao, wo_t, NTOK, D_MODEL, D_MODEL, pbuf);
  // combine + residual + fused rmsnorm2 -> out (f32) and hn (bf16)
  combine_o_norm<<<NTOK, 256, 0, stream>>>(pbuf, pbuf + (size_t)NTOK * D_MODEL,
                                           x, n2, out, hn);
  gemm_gu<<<1024, 512, GU_LDS_BYTES, stream>>>(hn, wg_t, wu_t, NTOK, FF_DIM, D_MODEL, gt);
  // down: split-K=2 (Kld=8192), partials again into qb/kb region
  gemm_dn<<<256, 512, DN_LDS_BYTES, stream>>>(gt, wd_t, NTOK, D_MODEL, FF_DIM, pbuf);
  combine_kernel<<<(NTOK * D_MODEL) / (256 * 8), 256, 0, stream>>>(
      pbuf, pbuf + (size_t)NTOK * D_MODEL, out);
}